// Round 10
// baseline (352.898 us; speedup 1.0000x reference)
//
#include <hip/hip_runtime.h>
#include <hip/hip_bf16.h>

typedef __hip_bfloat16 bf16;
typedef __attribute__((ext_vector_type(8))) short bf16x8;  // 8 bf16 in 4 VGPRs
typedef __attribute__((ext_vector_type(4))) float f32x4;

#define SEQ_LEN 2048
#define K_MAX   32
#define D_SPEC  256
#define D_MODEL 768
#define N_LAYERS 4
#define BATCH   2
#define MTOT    (BATCH * SEQ_LEN)       // 4096 rows (b*2048+t)
#define NU      (D_SPEC * K_MAX * 2)    // 16384 cols; n = (ok>>4)*32 + ri*16 + (ok&15)
#define NCOND   (2 * D_MODEL)           // 1536
#define NCHUNK  32

__device__ inline float b2f(bf16 h) { return __bfloat162float(h); }

__device__ inline void gload16(const void* gp, void* lp) {
  __builtin_amdgcn_global_load_lds((const __attribute__((address_space(1))) void*)gp,
                                   (__attribute__((address_space(3))) void*)lp, 16, 0, 0);
}

// LDS XOR swizzle (neutral but harmless; staging-side conflicts are structural).
__device__ inline int stage_c16(int lane) { return ((lane & 3) ^ ((lane >> 2) & 3) ^ ((lane >> 4) & 3)); }
__device__ inline int frag_off(int R, int q) {
  return (R << 5) + (((q ^ (R & 3) ^ ((R >> 2) & 3)) & 3) << 3);
}

// Full-rate DPP sum over each 16-lane row; result valid in lane 15 of each row.
__device__ inline float row_sum16(float v) {
  v += __int_as_float(__builtin_amdgcn_update_dpp(0, __float_as_int(v), 0x111, 0xF, 0xF, true)); // row_shr:1
  v += __int_as_float(__builtin_amdgcn_update_dpp(0, __float_as_int(v), 0x112, 0xF, 0xF, true)); // row_shr:2
  v += __int_as_float(__builtin_amdgcn_update_dpp(0, __float_as_int(v), 0x114, 0xF, 0xF, true)); // row_shr:4
  v += __int_as_float(__builtin_amdgcn_update_dpp(0, __float_as_int(v), 0x118, 0xF, 0xF, true)); // row_shr:8
  return v;
}

// ---------------------------------------------------------------------------
// setup: ONE dispatch doing all three prep jobs, split by blockIdx range.
//   [0,256)    prep_t: conv_w -> Bmat (gemm_p B^T) + W2 (wtot A) via LDS transpose
//   [256,512)  ybuild: per-chunk rotated x sums -> Y2 (wtot B^T)
//   [512,1024) prep2: permuted bf16 casts of w_shared / layer_w
// ---------------------------------------------------------------------------
__global__ __launch_bounds__(256) void setup(
    const bf16* __restrict__ conv_w, const bf16* __restrict__ x,
    const float* __restrict__ w_shared, const float* __restrict__ layer_w,
    bf16* __restrict__ Bmat, bf16* __restrict__ W2, bf16* __restrict__ Y2,
    bf16* __restrict__ wsb, bf16* __restrict__ lwb) {
  __shared__ bf16 L[256][66];        // only used by prep_t blocks
  const int bid = blockIdx.x;
  const int tid = threadIdx.x;

  if (bid < 256) {                   // ---- prep_t ----
    const int o = bid;
    const bf16* src = conv_w + (size_t)o * 16384;
#pragma unroll
    for (int it = 0; it < 8; ++it) {
      int v = tid + (it << 8);
      int e = v << 3;
      int i = e >> 6, kc = e & 63;
      uint4 d = *(const uint4*)(src + e);
      *(unsigned*)&L[i][kc]     = d.x;
      *(unsigned*)&L[i][kc + 2] = d.y;
      *(unsigned*)&L[i][kc + 4] = d.z;
      *(unsigned*)&L[i][kc + 6] = d.w;
    }
    __syncthreads();
#pragma unroll
    for (int kc = 0; kc < 64; ++kc) {
      int n = ((o << 1) + (kc >> 5)) * 32 + ((kc & 1) << 4) + ((kc >> 1) & 15);
      Bmat[((size_t)n << 8) + tid] = L[tid][kc];
    }
#pragma unroll
    for (int k = 0; k < 32; ++k) {
#pragma unroll
      for (int h = 0; h < 2; ++h) {
        int i2 = (h << 8) + tid;
        W2[((size_t)k << 17) + (o << 9) + i2] = L[i2 >> 1][(k << 1) + (i2 & 1)];
      }
    }
  } else if (bid < 512) {            // ---- ybuild ----
    const int yb = bid - 256;
    const int bc = yb >> 2, kg = (yb & 3) << 3;
    const int b = bc >> 5, c = bc & 31;
    const int t0 = c << 6;
    const int i = tid;
    const float c1f = -0.0030679615757712823f;
    float cs[8], sn[8], cd[8], sd[8], aC[8] = {}, aS[8] = {};
#pragma unroll
    for (int kk = 0; kk < 8; ++kk) {
      int k = kg + kk;
      __sincosf(c1f * (float)((t0 * k) & 2047), &sn[kk], &cs[kk]);
      __sincosf(c1f * (float)k, &sd[kk], &cd[kk]);
    }
    const bf16* xp = x + (((size_t)((b << 11) + t0)) << 8) + i;
#pragma unroll 4
    for (int t = 0; t < 64; ++t) {
      float xv = b2f(*xp); xp += D_SPEC;
#pragma unroll
      for (int kk = 0; kk < 8; ++kk) {
        aC[kk] += cs[kk] * xv; aS[kk] += sn[kk] * xv;
        float cn = cs[kk] * cd[kk] - sn[kk] * sd[kk];
        sn[kk] = sn[kk] * cd[kk] + cs[kk] * sd[kk];
        cs[kk] = cn;
      }
    }
#pragma unroll
    for (int kk = 0; kk < 8; ++kk) {
      int k = kg + kk;
      __hip_bfloat162 p0, p1;
      p0.x = __float2bfloat16(aC[kk]);  p0.y = __float2bfloat16(-aS[kk]);
      p1.x = __float2bfloat16(aS[kk]);  p1.y = __float2bfloat16(aC[kk]);
      *(__hip_bfloat162*)(Y2 + (((size_t)(k << 7) + (bc << 1)) << 9) + (i << 1)) = p0;
      *(__hip_bfloat162*)(Y2 + (((size_t)(k << 7) + (bc << 1) + 1) << 9) + (i << 1)) = p1;
    }
  } else {                           // ---- prep2 (row-permuted casts) ----
    int idx = (bid - 512) * 256 + tid;
    int stride = 512 * 256;
    for (int j = idx; j < D_MODEL * D_SPEC; j += stride) {
      int row = j >> 8, col = j & 255;
      int g = row >> 6, q = row & 63;
      int rt = (g << 6) + ((q & 15) << 2) + (q >> 4);
      wsb[j] = __float2bfloat16(w_shared[rt * D_SPEC + col]);
    }
    for (int j = idx; j < N_LAYERS * NCOND * D_MODEL; j += stride) {
      int zc = j / (NCOND * D_MODEL);
      int rem = j - zc * (NCOND * D_MODEL);
      int row = rem / D_MODEL, col = rem - row * D_MODEL;
      int g = row >> 6, q = row & 63;
      int rt = (g << 6) + ((q & 15) << 2) + (q >> 4);
      lwb[j] = __float2bfloat16(layer_w[(size_t)zc * NCOND * D_MODEL + rt * D_MODEL + col]);
    }
  }
}

// ---------------------------------------------------------------------------
// wtot: per-k complex GEMM totals[bc,o,k] = W[k] (256o x 512) @ Y2[k]^T (128col x 512)
// + self-term Y[bc,k,o]. Grid (1, 2, 32). Totals stay RAW per-chunk (no prefix pass).
// ---------------------------------------------------------------------------
__global__ __launch_bounds__(256, 4) void wtot(const bf16* __restrict__ W2,
                                               const bf16* __restrict__ Y2,
                                               float* __restrict__ totals) {
  __shared__ bf16 As[128 * 32];
  __shared__ bf16 Bs[128 * 32];
  const int tid = threadIdx.x;
  const int wave = tid >> 6, lane = tid & 63;
  const int wm = (wave >> 1) << 6, wn = (wave & 1) << 6;
  const int lrow = lane & 15, quad = lane >> 4;
  const int m0 = blockIdx.y << 7;
  const int z = blockIdx.z;
  const bf16* A = W2 + ((size_t)z << 17);
  const bf16* B = Y2 + ((size_t)z << 16);

  f32x4 acc[4][4] = {};
  for (int k0 = 0; k0 < 512; k0 += 32) {
#pragma unroll
    for (int c = 0; c < 2; ++c) {
      int rr = ((wave * 2 + c) << 4) + (lane >> 2);
      int cb = stage_c16(lane) << 4;
      int lq = (((wave * 2 + c) << 6) + lane) << 4;
      gload16((const char*)A + (((size_t)(m0 + rr) * 512 + k0) << 1) + cb, (char*)As + lq);
      gload16((const char*)B + (((size_t)rr * 512 + k0) << 1) + cb, (char*)Bs + lq);
    }
    __syncthreads();
    bf16x8 af[4], bfr[4];
#pragma unroll
    for (int i = 0; i < 4; ++i) {
      af[i]  = *(const bf16x8*)(As + frag_off(wm + (i << 4) + lrow, quad));
      bfr[i] = *(const bf16x8*)(Bs + frag_off(wn + (i << 4) + lrow, quad));
    }
#pragma unroll
    for (int mt = 0; mt < 4; ++mt)
#pragma unroll
      for (int nt = 0; nt < 4; ++nt)
        acc[mt][nt] = __builtin_amdgcn_mfma_f32_16x16x32_bf16(af[mt], bfr[nt], acc[mt][nt], 0, 0, 0);
    __syncthreads();
  }

#pragma unroll
  for (int mt = 0; mt < 4; ++mt)
#pragma unroll
    for (int nt = 0; nt < 4; ++nt)
#pragma unroll
      for (int r = 0; r < 4; ++r) {
        int o   = m0 + wm + (mt << 4) + (quad << 2) + r;
        int col = wn + (nt << 4) + lrow;
        int bc = col >> 1, comp = col & 1;
        float self = b2f(B[((size_t)col << 9) + (o << 1)]);
        totals[((((size_t)bc << 13) + (o << 5) + z) << 1) + comp] = acc[mt][nt][r] + self;
      }
}

// ---------------------------------------------------------------------------
// gemm_p: GEMM (x folded) -> self-computed inter-chunk carry (raw totals) ->
// twiddle via sincos recurrence -> prefix -> modReLU magnitude -> DPP k-mean.
// launch_bounds(256,4): force total regs (VGPR+AGPR) <= 128 -> 16 waves/CU.
// ---------------------------------------------------------------------------
__global__ __launch_bounds__(256, 4) void gemm_p(
    const bf16* __restrict__ A, const bf16* __restrict__ B, const bf16* __restrict__ x,
    const float* __restrict__ totals, const bf16* __restrict__ mrb, bf16* __restrict__ pooled) {
  __shared__ bf16 As[128 * 32];
  __shared__ bf16 Bs[128 * 32];
  const int tid = threadIdx.x;
  const int wave = tid >> 6, lane = tid & 63;
  const int wm = (wave >> 1) << 6, wn = (wave & 1) << 6;
  const int lrow = lane & 15, quad = lane >> 4;
  const int m0 = blockIdx.y << 7, n0 = blockIdx.x << 7;

  f32x4 acc[4][4] = {};
  for (int k0 = 0; k0 < D_SPEC; k0 += 32) {
#pragma unroll
    for (int c = 0; c < 2; ++c) {
      int rr = ((wave * 2 + c) << 4) + (lane >> 2);
      int cb = stage_c16(lane) << 4;
      int lq = (((wave * 2 + c) << 6) + lane) << 4;
      gload16((const char*)A + (((size_t)(m0 + rr) * D_SPEC + k0) << 1) + cb, (char*)As + lq);
      gload16((const char*)B + (((size_t)(n0 + rr) * D_SPEC + k0) << 1) + cb, (char*)Bs + lq);
    }
    __syncthreads();
    bf16x8 af[4], bfr[4];
#pragma unroll
    for (int i = 0; i < 4; ++i) {
      af[i]  = *(const bf16x8*)(As + frag_off(wm + (i << 4) + lrow, quad));
      bfr[i] = *(const bf16x8*)(Bs + frag_off(wn + (i << 4) + lrow, quad));
    }
#pragma unroll
    for (int mt = 0; mt < 4; ++mt)
#pragma unroll
      for (int nt = 0; nt < 4; ++nt)
        acc[mt][nt] = __builtin_amdgcn_mfma_f32_16x16x32_bf16(af[mt], bfr[nt], acc[mt][nt], 0, 0, 0);
    __syncthreads();
  }

  const int mbase = m0 + wm;                 // 64-row slab == exactly one chunk
  const int b = mbase >> 11;
  const int chunk = (mbase >> 6) & 31;
  const int g0 = (n0 + wn) >> 5;             // even
  const int o = g0 >> 1;                     // lane-uniform

  // fold x into the re-planes
#pragma unroll
  for (int mt = 0; mt < 4; ++mt)
#pragma unroll
    for (int r = 0; r < 4; ++r) {
      int m = mbase + (mt << 4) + (quad << 2) + r;
      float xv = b2f(x[((size_t)m << 8) + o]);
      acc[mt][0][r] += xv;
      acc[mt][2][r] += xv;
    }

  const float c1f = -0.0030679615757712823f;  // -2*pi/2048
  const float norm2 = 0.00048828125f;         // 1/2048
  const float biaso = b2f(mrb[o]);

  float cm[2], smv[2], c1v[2], s1v[2], c16v[2], s16v[2], carR[2] = {}, carI[2] = {};
#pragma unroll
  for (int j = 0; j < 2; ++j) {
    const int kk = lrow + (j << 4);
    const int t00 = (mbase & 2047) + (quad << 2);
    __sincosf(c1f * (float)((t00 * kk) & 2047), &smv[j], &cm[j]);
    __sincosf(c1f * (float)kk, &s1v[j], &c1v[j]);
    __sincosf(c1f * (float)((kk << 4) & 2047), &s16v[j], &c16v[j]);
    // exclusive inter-chunk carry from RAW chunk totals (tprefix eliminated)
    const int ok = ((g0 + j) << 4) + lrow;
    for (int cc = 0; cc < chunk; ++cc) {
      size_t tb = ((((size_t)(b * NCHUNK + cc)) << 13) + ok) << 1;
      carR[j] += totals[tb]; carI[j] += totals[tb + 1];
    }
  }

#pragma unroll
  for (int mt = 0; mt < 4; ++mt) {
    float prj[2][4], pij[2][4];
#pragma unroll
    for (int j = 0; j < 2; ++j) {
      float cr_ = cm[j], sr_ = smv[j];
      float vr[4], vi[4];
#pragma unroll
      for (int r = 0; r < 4; ++r) {
        float ur = acc[mt][2 * j][r], ui = acc[mt][2 * j + 1][r];
        vr[r] = cr_ * ur - sr_ * ui;
        vi[r] = cr_ * ui + sr_ * ur;
        if (r < 3) { float cn = cr_ * c1v[j] - sr_ * s1v[j]; sr_ = sr_ * c1v[j] + cr_ * s1v[j]; cr_ = cn; }
      }
      vr[1] += vr[0]; vr[2] += vr[1]; vr[3] += vr[2];
      vi[1] += vi[0]; vi[2] += vi[1]; vi[3] += vi[2];
      float Qr = vr[3], Qi = vi[3];
      float arq = __shfl_xor(Qr, 16, 64), aiq = __shfl_xor(Qi, 16, 64);
      float brq = __shfl_xor(Qr, 32, 64), biq = __shfl_xor(Qi, 32, 64);
      float crq = __shfl_xor(brq, 16, 64), ciq = __shfl_xor(biq, 16, 64);  // Q at quad^3
      float Sr = 0.f, Si = 0.f;
      if (quad & 1) { Sr += arq; Si += aiq; }
      if (quad & 2) { Sr += brq + crq; Si += biq + ciq; }
      float Er = carR[j] + Sr, Ei = carI[j] + Si;
      carR[j] += Qr + arq + brq + crq;
      carI[j] += Qi + aiq + biq + ciq;
#pragma unroll
      for (int r = 0; r < 4; ++r) { prj[j][r] = vr[r] + Er; pij[j][r] = vi[r] + Ei; }
      float cn = cm[j] * c16v[j] - smv[j] * s16v[j];
      smv[j] = smv[j] * c16v[j] + cm[j] * s16v[j];
      cm[j] = cn;
    }
    float red[4];
#pragma unroll
    for (int r = 0; r < 4; ++r) {
      float nm = 0.f;
#pragma unroll
      for (int j = 0; j < 2; ++j) {
        float rr2 = prj[j][r] * prj[j][r] + pij[j][r] * pij[j][r];
        nm += fmaxf(__builtin_amdgcn_sqrtf(norm2 * rr2 + 1e-8f) - biaso, 0.f);
      }
      red[r] = row_sum16(nm);                 // valid at lrow==15
    }
    if (lrow == 15) {
#pragma unroll
      for (int r = 0; r < 4; ++r) {
        int m = mbase + (mt << 4) + (quad << 2) + r;
        pooled[((size_t)m << 8) + o] = __float2bfloat16(red[r] * (1.f / 32.f));
      }
    }
  }
}

// ---------------------------------------------------------------------------
// Plain GEMM for the two dense projections. B rows are PERMUTED in storage
// (see setup/prep2) so fragment (nt,lrow) = true column lrow*4+nt -> vector stores.
// EPI 1: +bias, SiLU, store packed bf16x4 ; EPI 2: +bias[z], store f32x4
// ---------------------------------------------------------------------------
template <int EPI>
__global__ __launch_bounds__(256, 4) void gemm_k(
    const bf16* __restrict__ A, const bf16* __restrict__ B, void* __restrict__ Cp,
    const float* __restrict__ bias, int N, int K,
    long long c_bstride, long long b_bstride, int bias_bstride) {
  __shared__ bf16 As[128 * 32];
  __shared__ bf16 Bs[128 * 32];
  const int tid = threadIdx.x;
  const int wave = tid >> 6, lane = tid & 63;
  const int wm = (wave >> 1) << 6, wn = (wave & 1) << 6;
  const int lrow = lane & 15, quad = lane >> 4;
  const int m0 = blockIdx.y << 7, n0 = blockIdx.x << 7;
  const int z = blockIdx.z;
  const bf16* Bz = B + (size_t)z * b_bstride;

  f32x4 acc[4][4] = {};
  for (int k0 = 0; k0 < K; k0 += 32) {
#pragma unroll
    for (int c = 0; c < 2; ++c) {
      int rr = ((wave * 2 + c) << 4) + (lane >> 2);
      int cb = stage_c16(lane) << 4;
      int lq = (((wave * 2 + c) << 6) + lane) << 4;
      gload16((const char*)A  + (((size_t)(m0 + rr) * K + k0) << 1) + cb, (char*)As + lq);
      gload16((const char*)Bz + (((size_t)(n0 + rr) * K + k0) << 1) + cb, (char*)Bs + lq);
    }
    __syncthreads();
    bf16x8 af[4], bfr[4];
#pragma unroll
    for (int i = 0; i < 4; ++i) {
      af[i]  = *(const bf16x8*)(As + frag_off(wm + (i << 4) + lrow, quad));
      bfr[i] = *(const bf16x8*)(Bs + frag_off(wn + (i << 4) + lrow, quad));
    }
#pragma unroll
    for (int mt = 0; mt < 4; ++mt)
#pragma unroll
      for (int nt = 0; nt < 4; ++nt)
        acc[mt][nt] = __builtin_amdgcn_mfma_f32_16x16x32_bf16(af[mt], bfr[nt], acc[mt][nt], 0, 0, 0);
    __syncthreads();
  }

  const int gnb = n0 + wn + (lrow << 2);       // 4 consecutive true columns
  f32x4 b4;
  if (EPI == 1) b4 = *(const f32x4*)(bias + gnb);
  else          b4 = *(const f32x4*)(bias + (size_t)z * bias_bstride + gnb);

#pragma unroll
  for (int mt = 0; mt < 4; ++mt) {
#pragma unroll
    for (int r = 0; r < 4; ++r) {
      int gm = m0 + wm + (mt << 4) + (quad << 2) + r;
      if (EPI == 1) {
        union { bf16 h[4]; uint2 u; } pk;
#pragma unroll
        for (int nt = 0; nt < 4; ++nt) {
          float v = acc[mt][nt][r] + b4[nt];
          v = v / (1.f + __expf(-v));                    // SiLU
          pk.h[nt] = __float2bfloat16(v);
        }
        *(uint2*)((bf16*)Cp + (size_t)gm * N + gnb) = pk.u;
      } else {
        f32x4 vv;
#pragma unroll
        for (int nt = 0; nt < 4; ++nt) vv[nt] = acc[mt][nt][r] + b4[nt];
        *(f32x4*)((float*)Cp + (size_t)z * c_bstride + (size_t)gm * N + gnb) = vv;
      }
    }
  }
}

// ---------------------------------------------------------------------------
extern "C" void kernel_launch(void* const* d_in, const int* in_sizes, int n_in,
                              void* d_out, int out_size, void* d_ws, size_t ws_size,
                              hipStream_t stream) {
  const bf16* x        = (const bf16*)d_in[0];
  const bf16* conv_w   = (const bf16*)d_in[1];
  const bf16* mrb      = (const bf16*)d_in[2];
  const float* w_shared = (const float*)d_in[3];
  const float* b_shared = (const float*)d_in[4];
  const float* layer_w  = (const float*)d_in[5];
  const float* layer_b  = (const float*)d_in[6];
  float* out = (float*)d_out;

  char* ws = (char*)d_ws;
  bf16* Bmat    = (bf16*)(ws);                // 8,388,608
  bf16* W2      = (bf16*)(ws + 8388608);      // 8,388,608   -> 16,777,216
  bf16* Y2      = (bf16*)(ws + 16777216);     // 4,194,304   -> 20,971,520
  float* totals = (float*)(ws + 20971520);    // 4,194,304   -> 25,165,824
  bf16* pooled  = (bf16*)(ws + 25165824);     // 2,097,152   -> 27,262,976
  bf16* wsb     = (bf16*)(ws + 27262976);     // 393,216     -> 27,656,192
  bf16* hidden  = (bf16*)(ws + 27656192);     // 6,291,456   -> 33,947,648
  bf16* lwb     = (bf16*)(ws + 33947648);     // 9,437,184   -> 43,384,832

  // one fused setup dispatch: prep_t (256) | ybuild (256) | prep2 (512)
  setup<<<1024, 256, 0, stream>>>(conv_w, x, w_shared, layer_w, Bmat, W2, Y2, wsb, lwb);

  // chunk totals (raw, per-chunk)
  wtot<<<dim3(1, 2, K_MAX), 256, 0, stream>>>(W2, Y2, totals);

  // big GEMM pass: recompute u, self-carry, prefix, modReLU, pool
  gemm_p<<<dim3(NU / 128, MTOT / 128, 1), 256, 0, stream>>>(x, Bmat, x, totals, mrb, pooled);

  // hidden = silu(pooled @ w_shared^T + b_shared)
  gemm_k<1><<<dim3(D_MODEL / 128, MTOT / 128, 1), 256, 0, stream>>>(
      pooled, wsb, hidden, b_shared, D_MODEL, D_SPEC, 0, 0, 0);

  // cond[l] = hidden @ layer_w[l]^T + layer_b[l]
  gemm_k<2><<<dim3(NCOND / 128, MTOT / 128, N_LAYERS), 256, 0, stream>>>(
      hidden, lwb, out, layer_b, NCOND, D_MODEL,
      (long long)MTOT * NCOND, (long long)NCOND * D_MODEL, NCOND);
}

// Round 11
// 291.331 us; speedup vs baseline: 1.2113x; 1.2113x over previous
//
#include <hip/hip_runtime.h>
#include <hip/hip_bf16.h>

typedef __hip_bfloat16 bf16;
typedef __attribute__((ext_vector_type(8))) short bf16x8;  // 8 bf16 in 4 VGPRs
typedef __attribute__((ext_vector_type(4))) float f32x4;

#define SEQ_LEN 2048
#define K_MAX   32
#define D_SPEC  256
#define D_MODEL 768
#define N_LAYERS 4
#define BATCH   2
#define MTOT    (BATCH * SEQ_LEN)       // 4096 rows (b*2048+t)
#define NU      (D_SPEC * K_MAX * 2)    // 16384 cols
#define NCOND   (2 * D_MODEL)           // 1536
#define NCHUNK  32

__device__ inline float b2f(bf16 h) { return __bfloat162float(h); }

__device__ inline void gload16(const void* gp, void* lp) {
  __builtin_amdgcn_global_load_lds((const __attribute__((address_space(1))) void*)gp,
                                   (__attribute__((address_space(3))) void*)lp, 16, 0, 0);
}

__device__ inline int stage_c16(int lane) { return ((lane & 3) ^ ((lane >> 2) & 3) ^ ((lane >> 4) & 3)); }
__device__ inline int frag_off(int R, int q) {
  return (R << 5) + (((q ^ (R & 3) ^ ((R >> 2) & 3)) & 3) << 3);
}

// Full-rate DPP sum over each 16-lane row; result valid in lane 15 of each row.
__device__ inline float row_sum16(float v) {
  v += __int_as_float(__builtin_amdgcn_update_dpp(0, __float_as_int(v), 0x111, 0xF, 0xF, true)); // row_shr:1
  v += __int_as_float(__builtin_amdgcn_update_dpp(0, __float_as_int(v), 0x112, 0xF, 0xF, true)); // row_shr:2
  v += __int_as_float(__builtin_amdgcn_update_dpp(0, __float_as_int(v), 0x114, 0xF, 0xF, true)); // row_shr:4
  v += __int_as_float(__builtin_amdgcn_update_dpp(0, __float_as_int(v), 0x118, 0xF, 0xF, true)); // row_shr:8
  return v;
}

// ---------------------------------------------------------------------------
// setup: ONE dispatch doing all three prep jobs, split by blockIdx range.
//   [0,256)    prep_t: conv_w -> Bmat (gemm_p B^T) + W2 (wtot A) via LDS transpose
//   [256,512)  ybuild: per-chunk rotated x sums -> Y2 (wtot B^T)
//   [512,1024) prep2: permuted bf16 casts of w_shared / layer_w
// ---------------------------------------------------------------------------
__global__ __launch_bounds__(256) void setup(
    const bf16* __restrict__ conv_w, const bf16* __restrict__ x,
    const float* __restrict__ w_shared, const float* __restrict__ layer_w,
    bf16* __restrict__ Bmat, bf16* __restrict__ W2, bf16* __restrict__ Y2,
    bf16* __restrict__ wsb, bf16* __restrict__ lwb) {
  __shared__ bf16 L[256][66];        // only used by prep_t blocks
  const int bid = blockIdx.x;
  const int tid = threadIdx.x;

  if (bid < 256) {                   // ---- prep_t ----
    const int o = bid;
    const bf16* src = conv_w + (size_t)o * 16384;
#pragma unroll
    for (int it = 0; it < 8; ++it) {
      int v = tid + (it << 8);
      int e = v << 3;
      int i = e >> 6, kc = e & 63;
      uint4 d = *(const uint4*)(src + e);
      *(unsigned*)&L[i][kc]     = d.x;
      *(unsigned*)&L[i][kc + 2] = d.y;
      *(unsigned*)&L[i][kc + 4] = d.z;
      *(unsigned*)&L[i][kc + 6] = d.w;
    }
    __syncthreads();
#pragma unroll
    for (int kc = 0; kc < 64; ++kc) {
      int n = ((o << 1) + (kc >> 5)) * 32 + ((kc & 1) << 4) + ((kc >> 1) & 15);
      Bmat[((size_t)n << 8) + tid] = L[tid][kc];
    }
#pragma unroll
    for (int k = 0; k < 32; ++k) {
#pragma unroll
      for (int h = 0; h < 2; ++h) {
        int i2 = (h << 8) + tid;
        W2[((size_t)k << 17) + (o << 9) + i2] = L[i2 >> 1][(k << 1) + (i2 & 1)];
      }
    }
  } else if (bid < 512) {            // ---- ybuild ----
    const int yb = bid - 256;
    const int bc = yb >> 2, kg = (yb & 3) << 3;
    const int b = bc >> 5, c = bc & 31;
    const int t0 = c << 6;
    const int i = tid;
    const float c1f = -0.0030679615757712823f;
    float cs[8], sn[8], cd[8], sd[8], aC[8] = {}, aS[8] = {};
#pragma unroll
    for (int kk = 0; kk < 8; ++kk) {
      int k = kg + kk;
      __sincosf(c1f * (float)((t0 * k) & 2047), &sn[kk], &cs[kk]);
      __sincosf(c1f * (float)k, &sd[kk], &cd[kk]);
    }
    const bf16* xp = x + (((size_t)((b << 11) + t0)) << 8) + i;
#pragma unroll 4
    for (int t = 0; t < 64; ++t) {
      float xv = b2f(*xp); xp += D_SPEC;
#pragma unroll
      for (int kk = 0; kk < 8; ++kk) {
        aC[kk] += cs[kk] * xv; aS[kk] += sn[kk] * xv;
        float cn = cs[kk] * cd[kk] - sn[kk] * sd[kk];
        sn[kk] = sn[kk] * cd[kk] + cs[kk] * sd[kk];
        cs[kk] = cn;
      }
    }
#pragma unroll
    for (int kk = 0; kk < 8; ++kk) {
      int k = kg + kk;
      __hip_bfloat162 p0, p1;
      p0.x = __float2bfloat16(aC[kk]);  p0.y = __float2bfloat16(-aS[kk]);
      p1.x = __float2bfloat16(aS[kk]);  p1.y = __float2bfloat16(aC[kk]);
      *(__hip_bfloat162*)(Y2 + (((size_t)(k << 7) + (bc << 1)) << 9) + (i << 1)) = p0;
      *(__hip_bfloat162*)(Y2 + (((size_t)(k << 7) + (bc << 1) + 1) << 9) + (i << 1)) = p1;
    }
  } else {                           // ---- prep2 (row-permuted casts) ----
    int idx = (bid - 512) * 256 + tid;
    int stride = 512 * 256;
    for (int j = idx; j < D_MODEL * D_SPEC; j += stride) {
      int row = j >> 8, col = j & 255;
      int g = row >> 6, q = row & 63;
      int rt = (g << 6) + ((q & 15) << 2) + (q >> 4);
      wsb[j] = __float2bfloat16(w_shared[rt * D_SPEC + col]);
    }
    for (int j = idx; j < N_LAYERS * NCOND * D_MODEL; j += stride) {
      int zc = j / (NCOND * D_MODEL);
      int rem = j - zc * (NCOND * D_MODEL);
      int row = rem / D_MODEL, col = rem - row * D_MODEL;
      int g = row >> 6, q = row & 63;
      int rt = (g << 6) + ((q & 15) << 2) + (q >> 4);
      lwb[j] = __float2bfloat16(layer_w[(size_t)zc * NCOND * D_MODEL + rt * D_MODEL + col]);
    }
  }
}

// ---------------------------------------------------------------------------
// wtot: per-k complex GEMM totals[bc,o,k] = W[k] (256o x 512) @ Y2[k]^T (128col x 512)
// + self-term Y[bc,k,o]. Grid (1, 2, 32).
// ---------------------------------------------------------------------------
__global__ __launch_bounds__(256, 2) void wtot(const bf16* __restrict__ W2,
                                               const bf16* __restrict__ Y2,
                                               float* __restrict__ totals) {
  __shared__ bf16 As[128 * 32];
  __shared__ bf16 Bs[128 * 32];
  const int tid = threadIdx.x;
  const int wave = tid >> 6, lane = tid & 63;
  const int wm = (wave >> 1) << 6, wn = (wave & 1) << 6;
  const int lrow = lane & 15, quad = lane >> 4;
  const int m0 = blockIdx.y << 7;
  const int z = blockIdx.z;
  const bf16* A = W2 + ((size_t)z << 17);
  const bf16* B = Y2 + ((size_t)z << 16);

  f32x4 acc[4][4] = {};
  for (int k0 = 0; k0 < 512; k0 += 32) {
#pragma unroll
    for (int c = 0; c < 2; ++c) {
      int rr = ((wave * 2 + c) << 4) + (lane >> 2);
      int cb = stage_c16(lane) << 4;
      int lq = (((wave * 2 + c) << 6) + lane) << 4;
      gload16((const char*)A + (((size_t)(m0 + rr) * 512 + k0) << 1) + cb, (char*)As + lq);
      gload16((const char*)B + (((size_t)rr * 512 + k0) << 1) + cb, (char*)Bs + lq);
    }
    __syncthreads();
    bf16x8 af[4], bfr[4];
#pragma unroll
    for (int i = 0; i < 4; ++i) {
      af[i]  = *(const bf16x8*)(As + frag_off(wm + (i << 4) + lrow, quad));
      bfr[i] = *(const bf16x8*)(Bs + frag_off(wn + (i << 4) + lrow, quad));
    }
#pragma unroll
    for (int mt = 0; mt < 4; ++mt)
#pragma unroll
      for (int nt = 0; nt < 4; ++nt)
        acc[mt][nt] = __builtin_amdgcn_mfma_f32_16x16x32_bf16(af[mt], bfr[nt], acc[mt][nt], 0, 0, 0);
    __syncthreads();
  }

#pragma unroll
  for (int mt = 0; mt < 4; ++mt)
#pragma unroll
    for (int nt = 0; nt < 4; ++nt)
#pragma unroll
      for (int r = 0; r < 4; ++r) {
        int o   = m0 + wm + (mt << 4) + (quad << 2) + r;
        int col = wn + (nt << 4) + lrow;
        int bc = col >> 1, comp = col & 1;
        float self = b2f(B[((size_t)col << 9) + (o << 1)]);
        totals[((((size_t)bc << 13) + (o << 5) + z) << 1) + comp] = acc[mt][nt][r] + self;
      }
}

// In-place exclusive prefix over chunks for each of the 16384 chains.
__global__ void tprefix(float* __restrict__ totals) {
  int id = blockIdx.x * blockDim.x + threadIdx.x;   // (b<<13) + ok
  int b = id >> 13, ok = id & 8191;
  float sr = 0.f, si = 0.f;
  for (int cc = 0; cc < NCHUNK; ++cc) {
    size_t idx = ((((size_t)(b * NCHUNK + cc)) << 13) + ok) << 1;
    float tr = totals[idx], ti = totals[idx + 1];
    totals[idx] = sr; totals[idx + 1] = si;
    sr += tr; si += ti;
  }
}

// ---------------------------------------------------------------------------
// gemm_p: GEMM (x folded) -> twiddle via sincos recurrence -> prefix (register
// scan + independent xor-shuffle quad scan, seeded with inter-chunk carry) ->
// modReLU magnitude -> DPP k-mean -> pooled.  (R8-proven config: (256,3).)
// ---------------------------------------------------------------------------
__global__ __launch_bounds__(256, 3) void gemm_p(
    const bf16* __restrict__ A, const bf16* __restrict__ B, const bf16* __restrict__ x,
    const float* __restrict__ totals, const bf16* __restrict__ mrb, bf16* __restrict__ pooled) {
  __shared__ bf16 As[128 * 32];
  __shared__ bf16 Bs[128 * 32];
  const int tid = threadIdx.x;
  const int wave = tid >> 6, lane = tid & 63;
  const int wm = (wave >> 1) << 6, wn = (wave & 1) << 6;
  const int lrow = lane & 15, quad = lane >> 4;
  const int m0 = blockIdx.y << 7, n0 = blockIdx.x << 7;

  f32x4 acc[4][4] = {};
  for (int k0 = 0; k0 < D_SPEC; k0 += 32) {
#pragma unroll
    for (int c = 0; c < 2; ++c) {
      int rr = ((wave * 2 + c) << 4) + (lane >> 2);
      int cb = stage_c16(lane) << 4;
      int lq = (((wave * 2 + c) << 6) + lane) << 4;
      gload16((const char*)A + (((size_t)(m0 + rr) * D_SPEC + k0) << 1) + cb, (char*)As + lq);
      gload16((const char*)B + (((size_t)(n0 + rr) * D_SPEC + k0) << 1) + cb, (char*)Bs + lq);
    }
    __syncthreads();
    bf16x8 af[4], bfr[4];
#pragma unroll
    for (int i = 0; i < 4; ++i) {
      af[i]  = *(const bf16x8*)(As + frag_off(wm + (i << 4) + lrow, quad));
      bfr[i] = *(const bf16x8*)(Bs + frag_off(wn + (i << 4) + lrow, quad));
    }
#pragma unroll
    for (int mt = 0; mt < 4; ++mt)
#pragma unroll
      for (int nt = 0; nt < 4; ++nt)
        acc[mt][nt] = __builtin_amdgcn_mfma_f32_16x16x32_bf16(af[mt], bfr[nt], acc[mt][nt], 0, 0, 0);
    __syncthreads();
  }

  const int mbase = m0 + wm;                 // 64-row slab == exactly one chunk
  const int b = mbase >> 11;
  const int chunk = (mbase >> 6) & 31;
  const int g0 = (n0 + wn) >> 5;             // even
  const int o = g0 >> 1;                     // lane-uniform

  // fold x into the re-planes
#pragma unroll
  for (int mt = 0; mt < 4; ++mt)
#pragma unroll
    for (int r = 0; r < 4; ++r) {
      int m = mbase + (mt << 4) + (quad << 2) + r;
      float xv = b2f(x[((size_t)m << 8) + o]);
      acc[mt][0][r] += xv;
      acc[mt][2][r] += xv;
    }

  const float c1f = -0.0030679615757712823f;  // -2*pi/2048
  const float norm2 = 0.00048828125f;         // 1/2048
  const float biaso = b2f(mrb[o]);

  float cm[2], smv[2], c1v[2], s1v[2], c16v[2], s16v[2], carR[2], carI[2];
#pragma unroll
  for (int j = 0; j < 2; ++j) {
    const int kk = lrow + (j << 4);
    const int t00 = (mbase & 2047) + (quad << 2);
    __sincosf(c1f * (float)((t00 * kk) & 2047), &smv[j], &cm[j]);
    __sincosf(c1f * (float)kk, &s1v[j], &c1v[j]);
    __sincosf(c1f * (float)((kk << 4) & 2047), &s16v[j], &c16v[j]);
    const int ok = ((g0 + j) << 4) + lrow;
    size_t tb = ((((size_t)(b * NCHUNK + chunk)) << 13) + ok) << 1;
    carR[j] = totals[tb]; carI[j] = totals[tb + 1];
  }

#pragma unroll
  for (int mt = 0; mt < 4; ++mt) {
    float prj[2][4], pij[2][4];
#pragma unroll
    for (int j = 0; j < 2; ++j) {
      float cr_ = cm[j], sr_ = smv[j];
      float vr[4], vi[4];
#pragma unroll
      for (int r = 0; r < 4; ++r) {
        float ur = acc[mt][2 * j][r], ui = acc[mt][2 * j + 1][r];
        vr[r] = cr_ * ur - sr_ * ui;
        vi[r] = cr_ * ui + sr_ * ur;
        if (r < 3) { float cn = cr_ * c1v[j] - sr_ * s1v[j]; sr_ = sr_ * c1v[j] + cr_ * s1v[j]; cr_ = cn; }
      }
      vr[1] += vr[0]; vr[2] += vr[1]; vr[3] += vr[2];
      vi[1] += vi[0]; vi[2] += vi[1]; vi[3] += vi[2];
      float Qr = vr[3], Qi = vi[3];
      float arq = __shfl_xor(Qr, 16, 64), aiq = __shfl_xor(Qi, 16, 64);
      float brq = __shfl_xor(Qr, 32, 64), biq = __shfl_xor(Qi, 32, 64);
      float crq = __shfl_xor(brq, 16, 64), ciq = __shfl_xor(biq, 16, 64);  // Q at quad^3
      float Sr = 0.f, Si = 0.f;
      if (quad & 1) { Sr += arq; Si += aiq; }
      if (quad & 2) { Sr += brq + crq; Si += biq + ciq; }
      float Er = carR[j] + Sr, Ei = carI[j] + Si;
      carR[j] += Qr + arq + brq + crq;
      carI[j] += Qi + aiq + biq + ciq;
#pragma unroll
      for (int r = 0; r < 4; ++r) { prj[j][r] = vr[r] + Er; pij[j][r] = vi[r] + Ei; }
      float cn = cm[j] * c16v[j] - smv[j] * s16v[j];
      smv[j] = smv[j] * c16v[j] + cm[j] * s16v[j];
      cm[j] = cn;
    }
    float red[4];
#pragma unroll
    for (int r = 0; r < 4; ++r) {
      float nm = 0.f;
#pragma unroll
      for (int j = 0; j < 2; ++j) {
        float rr2 = prj[j][r] * prj[j][r] + pij[j][r] * pij[j][r];
        nm += fmaxf(__builtin_amdgcn_sqrtf(norm2 * rr2 + 1e-8f) - biaso, 0.f);
      }
      red[r] = row_sum16(nm);                 // valid at lrow==15
    }
    if (lrow == 15) {
#pragma unroll
      for (int r = 0; r < 4; ++r) {
        int m = mbase + (mt << 4) + (quad << 2) + r;
        pooled[((size_t)m << 8) + o] = __float2bfloat16(red[r] * (1.f / 32.f));
      }
    }
  }
}

// ---------------------------------------------------------------------------
// Plain GEMM for the two dense projections. B rows are PERMUTED in storage
// (see setup/prep2) so fragment (nt,lrow) = true column lrow*4+nt -> vector stores.
// EPI 1: +bias, SiLU, store packed bf16x4 ; EPI 2: +bias[z], store f32x4
// ---------------------------------------------------------------------------
template <int EPI>
__global__ __launch_bounds__(256, 2) void gemm_k(
    const bf16* __restrict__ A, const bf16* __restrict__ B, void* __restrict__ Cp,
    const float* __restrict__ bias, int N, int K,
    long long c_bstride, long long b_bstride, int bias_bstride) {
  __shared__ bf16 As[128 * 32];
  __shared__ bf16 Bs[128 * 32];
  const int tid = threadIdx.x;
  const int wave = tid >> 6, lane = tid & 63;
  const int wm = (wave >> 1) << 6, wn = (wave & 1) << 6;
  const int lrow = lane & 15, quad = lane >> 4;
  const int m0 = blockIdx.y << 7, n0 = blockIdx.x << 7;
  const int z = blockIdx.z;
  const bf16* Bz = B + (size_t)z * b_bstride;

  f32x4 acc[4][4] = {};
  for (int k0 = 0; k0 < K; k0 += 32) {
#pragma unroll
    for (int c = 0; c < 2; ++c) {
      int rr = ((wave * 2 + c) << 4) + (lane >> 2);
      int cb = stage_c16(lane) << 4;
      int lq = (((wave * 2 + c) << 6) + lane) << 4;
      gload16((const char*)A  + (((size_t)(m0 + rr) * K + k0) << 1) + cb, (char*)As + lq);
      gload16((const char*)Bz + (((size_t)(n0 + rr) * K + k0) << 1) + cb, (char*)Bs + lq);
    }
    __syncthreads();
    bf16x8 af[4], bfr[4];
#pragma unroll
    for (int i = 0; i < 4; ++i) {
      af[i]  = *(const bf16x8*)(As + frag_off(wm + (i << 4) + lrow, quad));
      bfr[i] = *(const bf16x8*)(Bs + frag_off(wn + (i << 4) + lrow, quad));
    }
#pragma unroll
    for (int mt = 0; mt < 4; ++mt)
#pragma unroll
      for (int nt = 0; nt < 4; ++nt)
        acc[mt][nt] = __builtin_amdgcn_mfma_f32_16x16x32_bf16(af[mt], bfr[nt], acc[mt][nt], 0, 0, 0);
    __syncthreads();
  }

  const int gnb = n0 + wn + (lrow << 2);       // 4 consecutive true columns
  f32x4 b4;
  if (EPI == 1) b4 = *(const f32x4*)(bias + gnb);
  else          b4 = *(const f32x4*)(bias + (size_t)z * bias_bstride + gnb);

#pragma unroll
  for (int mt = 0; mt < 4; ++mt) {
#pragma unroll
    for (int r = 0; r < 4; ++r) {
      int gm = m0 + wm + (mt << 4) + (quad << 2) + r;
      if (EPI == 1) {
        union { bf16 h[4]; uint2 u; } pk;
#pragma unroll
        for (int nt = 0; nt < 4; ++nt) {
          float v = acc[mt][nt][r] + b4[nt];
          v = v / (1.f + __expf(-v));                    // SiLU
          pk.h[nt] = __float2bfloat16(v);
        }
        *(uint2*)((bf16*)Cp + (size_t)gm * N + gnb) = pk.u;
      } else {
        f32x4 vv;
#pragma unroll
        for (int nt = 0; nt < 4; ++nt) vv[nt] = acc[mt][nt][r] + b4[nt];
        *(f32x4*)((float*)Cp + (size_t)z * c_bstride + (size_t)gm * N + gnb) = vv;
      }
    }
  }
}

// ---------------------------------------------------------------------------
extern "C" void kernel_launch(void* const* d_in, const int* in_sizes, int n_in,
                              void* d_out, int out_size, void* d_ws, size_t ws_size,
                              hipStream_t stream) {
  const bf16* x        = (const bf16*)d_in[0];
  const bf16* conv_w   = (const bf16*)d_in[1];
  const bf16* mrb      = (const bf16*)d_in[2];
  const float* w_shared = (const float*)d_in[3];
  const float* b_shared = (const float*)d_in[4];
  const float* layer_w  = (const float*)d_in[5];
  const float* layer_b  = (const float*)d_in[6];
  float* out = (float*)d_out;

  char* ws = (char*)d_ws;
  bf16* Bmat    = (bf16*)(ws);                // 8,388,608
  bf16* W2      = (bf16*)(ws + 8388608);      // 8,388,608   -> 16,777,216
  bf16* Y2      = (bf16*)(ws + 16777216);     // 4,194,304   -> 20,971,520
  float* totals = (float*)(ws + 20971520);    // 4,194,304   -> 25,165,824
  bf16* pooled  = (bf16*)(ws + 25165824);     // 2,097,152   -> 27,262,976
  bf16* wsb     = (bf16*)(ws + 27262976);     // 393,216     -> 27,656,192
  bf16* hidden  = (bf16*)(ws + 27656192);     // 6,291,456   -> 33,947,648
  bf16* lwb     = (bf16*)(ws + 33947648);     // 9,437,184   -> 43,384,832

  // one fused setup dispatch: prep_t (256) | ybuild (256) | prep2 (512)
  setup<<<1024, 256, 0, stream>>>(conv_w, x, w_shared, layer_w, Bmat, W2, Y2, wsb, lwb);

  // chunk totals via the small algebraic path
  wtot<<<dim3(1, 2, K_MAX), 256, 0, stream>>>(W2, Y2, totals);
  tprefix<<<64, 256, 0, stream>>>(totals);

  // big GEMM pass: recompute u, prefix, modReLU, pool
  gemm_p<<<dim3(NU / 128, MTOT / 128, 1), 256, 0, stream>>>(x, Bmat, x, totals, mrb, pooled);

  // hidden = silu(pooled @ w_shared^T + b_shared)
  gemm_k<1><<<dim3(D_MODEL / 128, MTOT / 128, 1), 256, 0, stream>>>(
      pooled, wsb, hidden, b_shared, D_MODEL, D_SPEC, 0, 0, 0);

  // cond[l] = hidden @ layer_w[l]^T + layer_b[l]
  gemm_k<2><<<dim3(NCOND / 128, MTOT / 128, N_LAYERS), 256, 0, stream>>>(
      hidden, lwb, out, layer_b, NCOND, D_MODEL,
      (long long)MTOT * NCOND, (long long)NCOND * D_MODEL, NCOND);
}

// Round 12
// 290.224 us; speedup vs baseline: 1.2160x; 1.0038x over previous
//
#include <hip/hip_runtime.h>
#include <hip/hip_bf16.h>

typedef __hip_bfloat16 bf16;
typedef __attribute__((ext_vector_type(8))) short bf16x8;  // 8 bf16 in 4 VGPRs
typedef __attribute__((ext_vector_type(4))) float f32x4;

#define SEQ_LEN 2048
#define K_MAX   32
#define D_SPEC  256
#define D_MODEL 768
#define N_LAYERS 4
#define BATCH   2
#define MTOT    (BATCH * SEQ_LEN)       // 4096 rows (b*2048+t)
#define NU      (D_SPEC * K_MAX * 2)    // 16384 cols
#define NCOND   (2 * D_MODEL)           // 1536
#define NCHUNK  32

__device__ inline float b2f(bf16 h) { return __bfloat162float(h); }

__device__ inline void gload16(const void* gp, void* lp) {
  __builtin_amdgcn_global_load_lds((const __attribute__((address_space(1))) void*)gp,
                                   (__attribute__((address_space(3))) void*)lp, 16, 0, 0);
}

__device__ inline int stage_c16(int lane) { return ((lane & 3) ^ ((lane >> 2) & 3) ^ ((lane >> 4) & 3)); }
__device__ inline int frag_off(int R, int q) {
  return (R << 5) + (((q ^ (R & 3) ^ ((R >> 2) & 3)) & 3) << 3);
}

// Full-rate DPP sum over each 16-lane row; result valid in lane 15 of each row.
__device__ inline float row_sum16(float v) {
  v += __int_as_float(__builtin_amdgcn_update_dpp(0, __float_as_int(v), 0x111, 0xF, 0xF, true)); // row_shr:1
  v += __int_as_float(__builtin_amdgcn_update_dpp(0, __float_as_int(v), 0x112, 0xF, 0xF, true)); // row_shr:2
  v += __int_as_float(__builtin_amdgcn_update_dpp(0, __float_as_int(v), 0x114, 0xF, 0xF, true)); // row_shr:4
  v += __int_as_float(__builtin_amdgcn_update_dpp(0, __float_as_int(v), 0x118, 0xF, 0xF, true)); // row_shr:8
  return v;
}

// ---------------------------------------------------------------------------
// setup: ONE dispatch doing all three prep jobs, split by blockIdx range.
//   [0,256)    prep_t: conv_w -> Bmat (gemm_p B^T) + W2 (wtot A) via LDS transpose
//   [256,512)  ybuild: per-chunk rotated x sums -> Y2 (wtot B^T)
//   [512,1024) prep2: permuted bf16 casts of w_shared / layer_w
// ---------------------------------------------------------------------------
__global__ __launch_bounds__(256) void setup(
    const bf16* __restrict__ conv_w, const bf16* __restrict__ x,
    const float* __restrict__ w_shared, const float* __restrict__ layer_w,
    bf16* __restrict__ Bmat, bf16* __restrict__ W2, bf16* __restrict__ Y2,
    bf16* __restrict__ wsb, bf16* __restrict__ lwb) {
  __shared__ bf16 L[256][66];        // only used by prep_t blocks
  const int bid = blockIdx.x;
  const int tid = threadIdx.x;

  if (bid < 256) {                   // ---- prep_t ----
    const int o = bid;
    const bf16* src = conv_w + (size_t)o * 16384;
#pragma unroll
    for (int it = 0; it < 8; ++it) {
      int v = tid + (it << 8);
      int e = v << 3;
      int i = e >> 6, kc = e & 63;
      uint4 d = *(const uint4*)(src + e);
      *(unsigned*)&L[i][kc]     = d.x;
      *(unsigned*)&L[i][kc + 2] = d.y;
      *(unsigned*)&L[i][kc + 4] = d.z;
      *(unsigned*)&L[i][kc + 6] = d.w;
    }
    __syncthreads();
#pragma unroll
    for (int kc = 0; kc < 64; ++kc) {
      int n = ((o << 1) + (kc >> 5)) * 32 + ((kc & 1) << 4) + ((kc >> 1) & 15);
      Bmat[((size_t)n << 8) + tid] = L[tid][kc];
    }
#pragma unroll
    for (int k = 0; k < 32; ++k) {
#pragma unroll
      for (int h = 0; h < 2; ++h) {
        int i2 = (h << 8) + tid;
        W2[((size_t)k << 17) + (o << 9) + i2] = L[i2 >> 1][(k << 1) + (i2 & 1)];
      }
    }
  } else if (bid < 512) {            // ---- ybuild ----
    const int yb = bid - 256;
    const int bc = yb >> 2, kg = (yb & 3) << 3;
    const int b = bc >> 5, c = bc & 31;
    const int t0 = c << 6;
    const int i = tid;
    const float c1f = -0.0030679615757712823f;
    float cs[8], sn[8], cd[8], sd[8], aC[8] = {}, aS[8] = {};
#pragma unroll
    for (int kk = 0; kk < 8; ++kk) {
      int k = kg + kk;
      __sincosf(c1f * (float)((t0 * k) & 2047), &sn[kk], &cs[kk]);
      __sincosf(c1f * (float)k, &sd[kk], &cd[kk]);
    }
    const bf16* xp = x + (((size_t)((b << 11) + t0)) << 8) + i;
#pragma unroll 4
    for (int t = 0; t < 64; ++t) {
      float xv = b2f(*xp); xp += D_SPEC;
#pragma unroll
      for (int kk = 0; kk < 8; ++kk) {
        aC[kk] += cs[kk] * xv; aS[kk] += sn[kk] * xv;
        float cn = cs[kk] * cd[kk] - sn[kk] * sd[kk];
        sn[kk] = sn[kk] * cd[kk] + cs[kk] * sd[kk];
        cs[kk] = cn;
      }
    }
#pragma unroll
    for (int kk = 0; kk < 8; ++kk) {
      int k = kg + kk;
      __hip_bfloat162 p0, p1;
      p0.x = __float2bfloat16(aC[kk]);  p0.y = __float2bfloat16(-aS[kk]);
      p1.x = __float2bfloat16(aS[kk]);  p1.y = __float2bfloat16(aC[kk]);
      *(__hip_bfloat162*)(Y2 + (((size_t)(k << 7) + (bc << 1)) << 9) + (i << 1)) = p0;
      *(__hip_bfloat162*)(Y2 + (((size_t)(k << 7) + (bc << 1) + 1) << 9) + (i << 1)) = p1;
    }
  } else {                           // ---- prep2 (row-permuted casts) ----
    int idx = (bid - 512) * 256 + tid;
    int stride = 512 * 256;
    for (int j = idx; j < D_MODEL * D_SPEC; j += stride) {
      int row = j >> 8, col = j & 255;
      int g = row >> 6, q = row & 63;
      int rt = (g << 6) + ((q & 15) << 2) + (q >> 4);
      wsb[j] = __float2bfloat16(w_shared[rt * D_SPEC + col]);
    }
    for (int j = idx; j < N_LAYERS * NCOND * D_MODEL; j += stride) {
      int zc = j / (NCOND * D_MODEL);
      int rem = j - zc * (NCOND * D_MODEL);
      int row = rem / D_MODEL, col = rem - row * D_MODEL;
      int g = row >> 6, q = row & 63;
      int rt = (g << 6) + ((q & 15) << 2) + (q >> 4);
      lwb[j] = __float2bfloat16(layer_w[(size_t)zc * NCOND * D_MODEL + rt * D_MODEL + col]);
    }
  }
}

// ---------------------------------------------------------------------------
// wtot: per-k complex GEMM totals[bc,o,k] = W[k] (256o x 512) @ Y2[k]^T (128col x 512)
// + self-term Y[bc,k,o]. Grid (1, 2, 32).
// ---------------------------------------------------------------------------
__global__ __launch_bounds__(256, 2) void wtot(const bf16* __restrict__ W2,
                                               const bf16* __restrict__ Y2,
                                               float* __restrict__ totals) {
  __shared__ bf16 As[128 * 32];
  __shared__ bf16 Bs[128 * 32];
  const int tid = threadIdx.x;
  const int wave = tid >> 6, lane = tid & 63;
  const int wm = (wave >> 1) << 6, wn = (wave & 1) << 6;
  const int lrow = lane & 15, quad = lane >> 4;
  const int m0 = blockIdx.y << 7;
  const int z = blockIdx.z;
  const bf16* A = W2 + ((size_t)z << 17);
  const bf16* B = Y2 + ((size_t)z << 16);

  f32x4 acc[4][4] = {};
  for (int k0 = 0; k0 < 512; k0 += 32) {
#pragma unroll
    for (int c = 0; c < 2; ++c) {
      int rr = ((wave * 2 + c) << 4) + (lane >> 2);
      int cb = stage_c16(lane) << 4;
      int lq = (((wave * 2 + c) << 6) + lane) << 4;
      gload16((const char*)A + (((size_t)(m0 + rr) * 512 + k0) << 1) + cb, (char*)As + lq);
      gload16((const char*)B + (((size_t)rr * 512 + k0) << 1) + cb, (char*)Bs + lq);
    }
    __syncthreads();
    bf16x8 af[4], bfr[4];
#pragma unroll
    for (int i = 0; i < 4; ++i) {
      af[i]  = *(const bf16x8*)(As + frag_off(wm + (i << 4) + lrow, quad));
      bfr[i] = *(const bf16x8*)(Bs + frag_off(wn + (i << 4) + lrow, quad));
    }
#pragma unroll
    for (int mt = 0; mt < 4; ++mt)
#pragma unroll
      for (int nt = 0; nt < 4; ++nt)
        acc[mt][nt] = __builtin_amdgcn_mfma_f32_16x16x32_bf16(af[mt], bfr[nt], acc[mt][nt], 0, 0, 0);
    __syncthreads();
  }

#pragma unroll
  for (int mt = 0; mt < 4; ++mt)
#pragma unroll
    for (int nt = 0; nt < 4; ++nt)
#pragma unroll
      for (int r = 0; r < 4; ++r) {
        int o   = m0 + wm + (mt << 4) + (quad << 2) + r;
        int col = wn + (nt << 4) + lrow;
        int bc = col >> 1, comp = col & 1;
        float self = b2f(B[((size_t)col << 9) + (o << 1)]);
        totals[((((size_t)bc << 13) + (o << 5) + z) << 1) + comp] = acc[mt][nt][r] + self;
      }
}

// In-place exclusive prefix over chunks for each of the 16384 chains.
__global__ void tprefix(float* __restrict__ totals) {
  int id = blockIdx.x * blockDim.x + threadIdx.x;   // (b<<13) + ok
  int b = id >> 13, ok = id & 8191;
  float sr = 0.f, si = 0.f;
  for (int cc = 0; cc < NCHUNK; ++cc) {
    size_t idx = ((((size_t)(b * NCHUNK + cc)) << 13) + ok) << 1;
    float tr = totals[idx], ti = totals[idx + 1];
    totals[idx] = sr; totals[idx + 1] = si;
    sr += tr; si += ti;
  }
}

// ---------------------------------------------------------------------------
// gemm_p: GEMM with A-ROW PERMUTATION so each lane-quad owns 16 CONTIGUOUS t:
// stored slab-row s holds true row perm(s) = ((s>>2)&3)*16 + (s>>4)*4 + (s&3).
// Epilogue: single tw^1 rotation recurrence + register prefix over 16 values +
// ONE cross-quad shuffle scan per j (was 4) -> modReLU -> DPP k-mean.
// ---------------------------------------------------------------------------
__global__ __launch_bounds__(256, 3) void gemm_p(
    const bf16* __restrict__ A, const bf16* __restrict__ B, const bf16* __restrict__ x,
    const float* __restrict__ totals, const bf16* __restrict__ mrb, bf16* __restrict__ pooled) {
  __shared__ bf16 As[128 * 32];
  __shared__ bf16 Bs[128 * 32];
  const int tid = threadIdx.x;
  const int wave = tid >> 6, lane = tid & 63;
  const int wm = (wave >> 1) << 6, wn = (wave & 1) << 6;
  const int lrow = lane & 15, quad = lane >> 4;
  const int m0 = blockIdx.y << 7, n0 = blockIdx.x << 7;

  f32x4 acc[4][4] = {};
  for (int k0 = 0; k0 < D_SPEC; k0 += 32) {
#pragma unroll
    for (int c = 0; c < 2; ++c) {
      int rrt = ((wave * 2 + c) << 4) + (lane >> 2);     // LDS tile row
      int s = rrt & 63;
      int rA = (rrt & 64) + (((s >> 2) & 3) << 4) + ((s >> 4) << 2) + (s & 3);  // permuted A row
      int cb = stage_c16(lane) << 4;
      int lq = (((wave * 2 + c) << 6) + lane) << 4;
      gload16((const char*)A + (((size_t)(m0 + rA) * D_SPEC + k0) << 1) + cb, (char*)As + lq);
      gload16((const char*)B + (((size_t)(n0 + rrt) * D_SPEC + k0) << 1) + cb, (char*)Bs + lq);
    }
    __syncthreads();
    bf16x8 af[4], bfr[4];
#pragma unroll
    for (int i = 0; i < 4; ++i) {
      af[i]  = *(const bf16x8*)(As + frag_off(wm + (i << 4) + lrow, quad));
      bfr[i] = *(const bf16x8*)(Bs + frag_off(wn + (i << 4) + lrow, quad));
    }
#pragma unroll
    for (int mt = 0; mt < 4; ++mt)
#pragma unroll
      for (int nt = 0; nt < 4; ++nt)
        acc[mt][nt] = __builtin_amdgcn_mfma_f32_16x16x32_bf16(af[mt], bfr[nt], acc[mt][nt], 0, 0, 0);
    __syncthreads();
  }

  const int mbase = m0 + wm;                 // 64-row slab == exactly one chunk
  const int b = mbase >> 11;
  const int chunk = (mbase >> 6) & 31;
  const int g0 = (n0 + wn) >> 5;             // even
  const int o = g0 >> 1;                     // lane-uniform

  // fold x into the re-planes; true t of (mt,r) = quad*16 + mt*4 + r
#pragma unroll
  for (int mt = 0; mt < 4; ++mt)
#pragma unroll
    for (int r = 0; r < 4; ++r) {
      int m = mbase + (quad << 4) + (mt << 2) + r;
      float xv = b2f(x[((size_t)m << 8) + o]);
      acc[mt][0][r] += xv;
      acc[mt][2][r] += xv;
    }

  const float c1f = -0.0030679615757712823f;  // -2*pi/2048
  const float norm2 = 0.00048828125f;         // 1/2048
  const float biaso = b2f(mrb[o]);

  float red[4][4] = {};
#pragma unroll
  for (int j = 0; j < 2; ++j) {
    const int kk = lrow + (j << 4);
    const int t00 = (mbase & 2047) + (quad << 4);
    float c_, s_, c1v, s1v;
    __sincosf(c1f * (float)((t00 * kk) & 2047), &s_, &c_);
    __sincosf(c1f * (float)kk, &s1v, &c1v);
    const int ok = ((g0 + j) << 4) + lrow;
    size_t tb = ((((size_t)(b * NCHUNK + chunk)) << 13) + ok) << 1;
    float carR = totals[tb], carI = totals[tb + 1];

    float vr[4][4], vi[4][4];
    float runR = 0.f, runI = 0.f;
#pragma unroll
    for (int mt = 0; mt < 4; ++mt)
#pragma unroll
      for (int r = 0; r < 4; ++r) {          // t increases by 1 each step
        float ur = acc[mt][2 * j][r], ui = acc[mt][2 * j + 1][r];
        runR += c_ * ur - s_ * ui;
        runI += c_ * ui + s_ * ur;
        vr[mt][r] = runR; vi[mt][r] = runI;
        float cn = c_ * c1v - s_ * s1v; s_ = s_ * c1v + c_ * s1v; c_ = cn;
      }
    // single cross-quad exclusive scan of 16-t segment totals
    float Qr = runR, Qi = runI;
    float arq = __shfl_xor(Qr, 16, 64), aiq = __shfl_xor(Qi, 16, 64);
    float brq = __shfl_xor(Qr, 32, 64), biq = __shfl_xor(Qi, 32, 64);
    float crq = __shfl_xor(brq, 16, 64), ciq = __shfl_xor(biq, 16, 64);
    float Sr = 0.f, Si = 0.f;
    if (quad & 1) { Sr += arq; Si += aiq; }
    if (quad & 2) { Sr += brq + crq; Si += biq + ciq; }
    float Er = carR + Sr, Ei = carI + Si;
#pragma unroll
    for (int mt = 0; mt < 4; ++mt)
#pragma unroll
      for (int r = 0; r < 4; ++r) {
        float pr = vr[mt][r] + Er, pi = vi[mt][r] + Ei;
        float rr2 = pr * pr + pi * pi;
        red[mt][r] += fmaxf(__builtin_amdgcn_sqrtf(norm2 * rr2 + 1e-8f) - biaso, 0.f);
      }
  }
#pragma unroll
  for (int mt = 0; mt < 4; ++mt)
#pragma unroll
    for (int r = 0; r < 4; ++r) {
      float v = row_sum16(red[mt][r]);        // valid at lrow==15
      if (lrow == 15) {
        int m = mbase + (quad << 4) + (mt << 2) + r;
        pooled[((size_t)m << 8) + o] = __float2bfloat16(v * (1.f / 32.f));
      }
    }
}

// ---------------------------------------------------------------------------
// Plain GEMM for the two dense projections. B rows are PERMUTED in storage
// (see setup/prep2) so fragment (nt,lrow) = true column lrow*4+nt -> vector stores.
// EPI 1: +bias, SiLU, store packed bf16x4 ; EPI 2: +bias[z], store f32x4
// ---------------------------------------------------------------------------
template <int EPI>
__global__ __launch_bounds__(256, 2) void gemm_k(
    const bf16* __restrict__ A, const bf16* __restrict__ B, void* __restrict__ Cp,
    const float* __restrict__ bias, int N, int K,
    long long c_bstride, long long b_bstride, int bias_bstride) {
  __shared__ bf16 As[128 * 32];
  __shared__ bf16 Bs[128 * 32];
  const int tid = threadIdx.x;
  const int wave = tid >> 6, lane = tid & 63;
  const int wm = (wave >> 1) << 6, wn = (wave & 1) << 6;
  const int lrow = lane & 15, quad = lane >> 4;
  const int m0 = blockIdx.y << 7, n0 = blockIdx.x << 7;
  const int z = blockIdx.z;
  const bf16* Bz = B + (size_t)z * b_bstride;

  f32x4 acc[4][4] = {};
  for (int k0 = 0; k0 < K; k0 += 32) {
#pragma unroll
    for (int c = 0; c < 2; ++c) {
      int rr = ((wave * 2 + c) << 4) + (lane >> 2);
      int cb = stage_c16(lane) << 4;
      int lq = (((wave * 2 + c) << 6) + lane) << 4;
      gload16((const char*)A  + (((size_t)(m0 + rr) * K + k0) << 1) + cb, (char*)As + lq);
      gload16((const char*)Bz + (((size_t)(n0 + rr) * K + k0) << 1) + cb, (char*)Bs + lq);
    }
    __syncthreads();
    bf16x8 af[4], bfr[4];
#pragma unroll
    for (int i = 0; i < 4; ++i) {
      af[i]  = *(const bf16x8*)(As + frag_off(wm + (i << 4) + lrow, quad));
      bfr[i] = *(const bf16x8*)(Bs + frag_off(wn + (i << 4) + lrow, quad));
    }
#pragma unroll
    for (int mt = 0; mt < 4; ++mt)
#pragma unroll
      for (int nt = 0; nt < 4; ++nt)
        acc[mt][nt] = __builtin_amdgcn_mfma_f32_16x16x32_bf16(af[mt], bfr[nt], acc[mt][nt], 0, 0, 0);
    __syncthreads();
  }

  const int gnb = n0 + wn + (lrow << 2);       // 4 consecutive true columns
  f32x4 b4;
  if (EPI == 1) b4 = *(const f32x4*)(bias + gnb);
  else          b4 = *(const f32x4*)(bias + (size_t)z * bias_bstride + gnb);

#pragma unroll
  for (int mt = 0; mt < 4; ++mt) {
#pragma unroll
    for (int r = 0; r < 4; ++r) {
      int gm = m0 + wm + (mt << 4) + (quad << 2) + r;
      if (EPI == 1) {
        union { bf16 h[4]; uint2 u; } pk;
#pragma unroll
        for (int nt = 0; nt < 4; ++nt) {
          float v = acc[mt][nt][r] + b4[nt];
          v = v / (1.f + __expf(-v));                    // SiLU
          pk.h[nt] = __float2bfloat16(v);
        }
        *(uint2*)((bf16*)Cp + (size_t)gm * N + gnb) = pk.u;
      } else {
        f32x4 vv;
#pragma unroll
        for (int nt = 0; nt < 4; ++nt) vv[nt] = acc[mt][nt][r] + b4[nt];
        *(f32x4*)((float*)Cp + (size_t)z * c_bstride + (size_t)gm * N + gnb) = vv;
      }
    }
  }
}

// ---------------------------------------------------------------------------
extern "C" void kernel_launch(void* const* d_in, const int* in_sizes, int n_in,
                              void* d_out, int out_size, void* d_ws, size_t ws_size,
                              hipStream_t stream) {
  const bf16* x        = (const bf16*)d_in[0];
  const bf16* conv_w   = (const bf16*)d_in[1];
  const bf16* mrb      = (const bf16*)d_in[2];
  const float* w_shared = (const float*)d_in[3];
  const float* b_shared = (const float*)d_in[4];
  const float* layer_w  = (const float*)d_in[5];
  const float* layer_b  = (const float*)d_in[6];
  float* out = (float*)d_out;

  char* ws = (char*)d_ws;
  bf16* Bmat    = (bf16*)(ws);                // 8,388,608
  bf16* W2      = (bf16*)(ws + 8388608);      // 8,388,608   -> 16,777,216
  bf16* Y2      = (bf16*)(ws + 16777216);     // 4,194,304   -> 20,971,520
  float* totals = (float*)(ws + 20971520);    // 4,194,304   -> 25,165,824
  bf16* pooled  = (bf16*)(ws + 25165824);     // 2,097,152   -> 27,262,976
  bf16* wsb     = (bf16*)(ws + 27262976);     // 393,216     -> 27,656,192
  bf16* hidden  = (bf16*)(ws + 27656192);     // 6,291,456   -> 33,947,648
  bf16* lwb     = (bf16*)(ws + 33947648);     // 9,437,184   -> 43,384,832

  // one fused setup dispatch: prep_t (256) | ybuild (256) | prep2 (512)
  setup<<<1024, 256, 0, stream>>>(conv_w, x, w_shared, layer_w, Bmat, W2, Y2, wsb, lwb);

  // chunk totals via the small algebraic path
  wtot<<<dim3(1, 2, K_MAX), 256, 0, stream>>>(W2, Y2, totals);
  tprefix<<<64, 256, 0, stream>>>(totals);

  // big GEMM pass: recompute u, prefix, modReLU, pool
  gemm_p<<<dim3(NU / 128, MTOT / 128, 1), 256, 0, stream>>>(x, Bmat, x, totals, mrb, pooled);

  // hidden = silu(pooled @ w_shared^T + b_shared)
  gemm_k<1><<<dim3(D_MODEL / 128, MTOT / 128, 1), 256, 0, stream>>>(
      pooled, wsb, hidden, b_shared, D_MODEL, D_SPEC, 0, 0, 0);

  // cond[l] = hidden @ layer_w[l]^T + layer_b[l]
  gemm_k<2><<<dim3(NCOND / 128, MTOT / 128, N_LAYERS), 256, 0, stream>>>(
      hidden, lwb, out, layer_b, NCOND, D_MODEL,
      (long long)MTOT * NCOND, (long long)NCOND * D_MODEL, NCOND);
}

// Round 13
// 268.255 us; speedup vs baseline: 1.3155x; 1.0819x over previous
//
#include <hip/hip_runtime.h>
#include <hip/hip_bf16.h>

typedef __hip_bfloat16 bf16;
typedef __attribute__((ext_vector_type(8))) short bf16x8;  // 8 bf16 in 4 VGPRs
typedef __attribute__((ext_vector_type(4))) float f32x4;

#define SEQ_LEN 2048
#define K_MAX   32
#define D_SPEC  256
#define D_MODEL 768
#define N_LAYERS 4
#define BATCH   2
#define MTOT    (BATCH * SEQ_LEN)       // 4096 rows (b*2048+t)
#define NU      (D_SPEC * K_MAX * 2)    // 16384 cols
#define NCOND   (2 * D_MODEL)           // 1536
#define NCHUNK  32

__device__ inline float b2f(bf16 h) { return __bfloat162float(h); }

__device__ inline void gload16(const void* gp, void* lp) {
  __builtin_amdgcn_global_load_lds((const __attribute__((address_space(1))) void*)gp,
                                   (__attribute__((address_space(3))) void*)lp, 16, 0, 0);
}

// (BK=32 helpers, still used by wtot)
__device__ inline int stage_c16(int lane) { return ((lane & 3) ^ ((lane >> 2) & 3) ^ ((lane >> 4) & 3)); }
__device__ inline int frag_off(int R, int q) {
  return (R << 5) + (((q ^ (R & 3) ^ ((R >> 2) & 3)) & 3) << 3);
}

// Full-rate DPP sum over each 16-lane row; result valid in lane 15 of each row.
__device__ inline float row_sum16(float v) {
  v += __int_as_float(__builtin_amdgcn_update_dpp(0, __float_as_int(v), 0x111, 0xF, 0xF, true)); // row_shr:1
  v += __int_as_float(__builtin_amdgcn_update_dpp(0, __float_as_int(v), 0x112, 0xF, 0xF, true)); // row_shr:2
  v += __int_as_float(__builtin_amdgcn_update_dpp(0, __float_as_int(v), 0x114, 0xF, 0xF, true)); // row_shr:4
  v += __int_as_float(__builtin_amdgcn_update_dpp(0, __float_as_int(v), 0x118, 0xF, 0xF, true)); // row_shr:8
  return v;
}

// ---------------------------------------------------------------------------
// setup: ONE dispatch doing all three prep jobs, split by blockIdx range.
// ---------------------------------------------------------------------------
__global__ __launch_bounds__(256) void setup(
    const bf16* __restrict__ conv_w, const bf16* __restrict__ x,
    const float* __restrict__ w_shared, const float* __restrict__ layer_w,
    bf16* __restrict__ Bmat, bf16* __restrict__ W2, bf16* __restrict__ Y2,
    bf16* __restrict__ wsb, bf16* __restrict__ lwb) {
  __shared__ bf16 L[256][66];        // only used by prep_t blocks
  const int bid = blockIdx.x;
  const int tid = threadIdx.x;

  if (bid < 256) {                   // ---- prep_t ----
    const int o = bid;
    const bf16* src = conv_w + (size_t)o * 16384;
#pragma unroll
    for (int it = 0; it < 8; ++it) {
      int v = tid + (it << 8);
      int e = v << 3;
      int i = e >> 6, kc = e & 63;
      uint4 d = *(const uint4*)(src + e);
      *(unsigned*)&L[i][kc]     = d.x;
      *(unsigned*)&L[i][kc + 2] = d.y;
      *(unsigned*)&L[i][kc + 4] = d.z;
      *(unsigned*)&L[i][kc + 6] = d.w;
    }
    __syncthreads();
#pragma unroll
    for (int kc = 0; kc < 64; ++kc) {
      int n = ((o << 1) + (kc >> 5)) * 32 + ((kc & 1) << 4) + ((kc >> 1) & 15);
      Bmat[((size_t)n << 8) + tid] = L[tid][kc];
    }
#pragma unroll
    for (int k = 0; k < 32; ++k) {
#pragma unroll
      for (int h = 0; h < 2; ++h) {
        int i2 = (h << 8) + tid;
        W2[((size_t)k << 17) + (o << 9) + i2] = L[i2 >> 1][(k << 1) + (i2 & 1)];
      }
    }
  } else if (bid < 512) {            // ---- ybuild ----
    const int yb = bid - 256;
    const int bc = yb >> 2, kg = (yb & 3) << 3;
    const int b = bc >> 5, c = bc & 31;
    const int t0 = c << 6;
    const int i = tid;
    const float c1f = -0.0030679615757712823f;
    float cs[8], sn[8], cd[8], sd[8], aC[8] = {}, aS[8] = {};
#pragma unroll
    for (int kk = 0; kk < 8; ++kk) {
      int k = kg + kk;
      __sincosf(c1f * (float)((t0 * k) & 2047), &sn[kk], &cs[kk]);
      __sincosf(c1f * (float)k, &sd[kk], &cd[kk]);
    }
    const bf16* xp = x + (((size_t)((b << 11) + t0)) << 8) + i;
#pragma unroll 4
    for (int t = 0; t < 64; ++t) {
      float xv = b2f(*xp); xp += D_SPEC;
#pragma unroll
      for (int kk = 0; kk < 8; ++kk) {
        aC[kk] += cs[kk] * xv; aS[kk] += sn[kk] * xv;
        float cn = cs[kk] * cd[kk] - sn[kk] * sd[kk];
        sn[kk] = sn[kk] * cd[kk] + cs[kk] * sd[kk];
        cs[kk] = cn;
      }
    }
#pragma unroll
    for (int kk = 0; kk < 8; ++kk) {
      int k = kg + kk;
      __hip_bfloat162 p0, p1;
      p0.x = __float2bfloat16(aC[kk]);  p0.y = __float2bfloat16(-aS[kk]);
      p1.x = __float2bfloat16(aS[kk]);  p1.y = __float2bfloat16(aC[kk]);
      *(__hip_bfloat162*)(Y2 + (((size_t)(k << 7) + (bc << 1)) << 9) + (i << 1)) = p0;
      *(__hip_bfloat162*)(Y2 + (((size_t)(k << 7) + (bc << 1) + 1) << 9) + (i << 1)) = p1;
    }
  } else {                           // ---- prep2 (row-permuted casts) ----
    int idx = (bid - 512) * 256 + tid;
    int stride = 512 * 256;
    for (int j = idx; j < D_MODEL * D_SPEC; j += stride) {
      int row = j >> 8, col = j & 255;
      int g = row >> 6, q = row & 63;
      int rt = (g << 6) + ((q & 15) << 2) + (q >> 4);
      wsb[j] = __float2bfloat16(w_shared[rt * D_SPEC + col]);
    }
    for (int j = idx; j < N_LAYERS * NCOND * D_MODEL; j += stride) {
      int zc = j / (NCOND * D_MODEL);
      int rem = j - zc * (NCOND * D_MODEL);
      int row = rem / D_MODEL, col = rem - row * D_MODEL;
      int g = row >> 6, q = row & 63;
      int rt = (g << 6) + ((q & 15) << 2) + (q >> 4);
      lwb[j] = __float2bfloat16(layer_w[(size_t)zc * NCOND * D_MODEL + rt * D_MODEL + col]);
    }
  }
}

// ---------------------------------------------------------------------------
// wtot: per-k complex GEMM totals[bc,o,k] = W[k] @ Y2[k]^T + self. (BK=32 core.)
// ---------------------------------------------------------------------------
__global__ __launch_bounds__(256, 2) void wtot(const bf16* __restrict__ W2,
                                               const bf16* __restrict__ Y2,
                                               float* __restrict__ totals) {
  __shared__ bf16 As[128 * 32];
  __shared__ bf16 Bs[128 * 32];
  const int tid = threadIdx.x;
  const int wave = tid >> 6, lane = tid & 63;
  const int wm = (wave >> 1) << 6, wn = (wave & 1) << 6;
  const int lrow = lane & 15, quad = lane >> 4;
  const int m0 = blockIdx.y << 7;
  const int z = blockIdx.z;
  const bf16* A = W2 + ((size_t)z << 17);
  const bf16* B = Y2 + ((size_t)z << 16);

  f32x4 acc[4][4] = {};
  for (int k0 = 0; k0 < 512; k0 += 32) {
#pragma unroll
    for (int c = 0; c < 2; ++c) {
      int rr = ((wave * 2 + c) << 4) + (lane >> 2);
      int cb = stage_c16(lane) << 4;
      int lq = (((wave * 2 + c) << 6) + lane) << 4;
      gload16((const char*)A + (((size_t)(m0 + rr) * 512 + k0) << 1) + cb, (char*)As + lq);
      gload16((const char*)B + (((size_t)rr * 512 + k0) << 1) + cb, (char*)Bs + lq);
    }
    __syncthreads();
    bf16x8 af[4], bfr[4];
#pragma unroll
    for (int i = 0; i < 4; ++i) {
      af[i]  = *(const bf16x8*)(As + frag_off(wm + (i << 4) + lrow, quad));
      bfr[i] = *(const bf16x8*)(Bs + frag_off(wn + (i << 4) + lrow, quad));
    }
#pragma unroll
    for (int mt = 0; mt < 4; ++mt)
#pragma unroll
      for (int nt = 0; nt < 4; ++nt)
        acc[mt][nt] = __builtin_amdgcn_mfma_f32_16x16x32_bf16(af[mt], bfr[nt], acc[mt][nt], 0, 0, 0);
    __syncthreads();
  }

#pragma unroll
  for (int mt = 0; mt < 4; ++mt)
#pragma unroll
    for (int nt = 0; nt < 4; ++nt)
#pragma unroll
      for (int r = 0; r < 4; ++r) {
        int o   = m0 + wm + (mt << 4) + (quad << 2) + r;
        int col = wn + (nt << 4) + lrow;
        int bc = col >> 1, comp = col & 1;
        float self = b2f(B[((size_t)col << 9) + (o << 1)]);
        totals[((((size_t)bc << 13) + (o << 5) + z) << 1) + comp] = acc[mt][nt][r] + self;
      }
}

// In-place exclusive prefix over chunks; one thread per (chain, component).
__global__ void tprefix(float* __restrict__ totals) {
  int id = blockIdx.x * blockDim.x + threadIdx.x;   // 32768 = (b, ok, comp)
  int comp = id & 1, ok = (id >> 1) & 8191, b = id >> 14;
  float s = 0.f;
  for (int cc = 0; cc < NCHUNK; ++cc) {
    size_t idx = (((((size_t)(b * NCHUNK + cc)) << 13) + ok) << 1) + comp;
    float t = totals[idx];
    totals[idx] = s;
    s += t;
  }
}

// ---------------------------------------------------------------------------
// gemm_p: BK=64 K-loop (half the barriers) + A-ROW PERMUTATION (quad owns 16
// contiguous t) + granule-XOR LDS swizzle. Epilogue: tw recurrence + register
// prefix + one cross-quad scan per j -> modReLU -> DPP k-mean.
// ---------------------------------------------------------------------------
__global__ __launch_bounds__(256, 3) void gemm_p(
    const bf16* __restrict__ A, const bf16* __restrict__ B, const bf16* __restrict__ x,
    const float* __restrict__ totals, const bf16* __restrict__ mrb, bf16* __restrict__ pooled) {
  __shared__ bf16 As[128 * 64];
  __shared__ bf16 Bs[128 * 64];
  const int tid = threadIdx.x;
  const int wave = tid >> 6, lane = tid & 63;
  const int wm = (wave >> 1) << 6, wn = (wave & 1) << 6;
  const int lrow = lane & 15, quad = lane >> 4;
  const int m0 = blockIdx.y << 7, n0 = blockIdx.x << 7;

  f32x4 acc[4][4] = {};
  for (int k0 = 0; k0 < D_SPEC; k0 += 64) {
#pragma unroll
    for (int c = 0; c < 4; ++c) {
      int slot = (((wave << 2) + c) << 6) + lane;
      int row = slot >> 3;
      int g = (slot & 7) ^ (row & 7);          // source granule (swizzle on source side)
      int s = row & 63;
      int rA = (row & 64) + (((s >> 2) & 3) << 4) + ((s >> 4) << 2) + (s & 3);  // permuted A row
      int lq = slot << 4;
      gload16((const char*)A + (((size_t)(m0 + rA)  * D_SPEC + k0 + (g << 3)) << 1), (char*)As + lq);
      gload16((const char*)B + (((size_t)(n0 + row) * D_SPEC + k0 + (g << 3)) << 1), (char*)Bs + lq);
    }
    __syncthreads();
#pragma unroll
    for (int kh = 0; kh < 2; ++kh) {
      bf16x8 af[4], bfr[4];
#pragma unroll
      for (int i = 0; i < 4; ++i) {
        int gg = ((((kh << 2) + quad) ^ (lrow & 7)) << 3);
        af[i]  = *(const bf16x8*)(As + ((wm + (i << 4) + lrow) << 6) + gg);
        bfr[i] = *(const bf16x8*)(Bs + ((wn + (i << 4) + lrow) << 6) + gg);
      }
#pragma unroll
      for (int mt = 0; mt < 4; ++mt)
#pragma unroll
        for (int nt = 0; nt < 4; ++nt)
          acc[mt][nt] = __builtin_amdgcn_mfma_f32_16x16x32_bf16(af[mt], bfr[nt], acc[mt][nt], 0, 0, 0);
    }
    __syncthreads();
  }

  const int mbase = m0 + wm;                 // 64-row slab == exactly one chunk
  const int b = mbase >> 11;
  const int chunk = (mbase >> 6) & 31;
  const int g0 = (n0 + wn) >> 5;             // even
  const int o = g0 >> 1;                     // lane-uniform

  // fold x into the re-planes; true t of (mt,r) = quad*16 + mt*4 + r
#pragma unroll
  for (int mt = 0; mt < 4; ++mt)
#pragma unroll
    for (int r = 0; r < 4; ++r) {
      int m = mbase + (quad << 4) + (mt << 2) + r;
      float xv = b2f(x[((size_t)m << 8) + o]);
      acc[mt][0][r] += xv;
      acc[mt][2][r] += xv;
    }

  const float c1f = -0.0030679615757712823f;  // -2*pi/2048
  const float norm2 = 0.00048828125f;         // 1/2048
  const float biaso = b2f(mrb[o]);

  float red[4][4] = {};
#pragma unroll
  for (int j = 0; j < 2; ++j) {
    const int kk = lrow + (j << 4);
    const int t00 = (mbase & 2047) + (quad << 4);
    float c_, s_, c1v, s1v;
    __sincosf(c1f * (float)((t00 * kk) & 2047), &s_, &c_);
    __sincosf(c1f * (float)kk, &s1v, &c1v);
    const int ok = ((g0 + j) << 4) + lrow;
    size_t tb = ((((size_t)(b * NCHUNK + chunk)) << 13) + ok) << 1;
    float carR = totals[tb], carI = totals[tb + 1];

    float vr[4][4], vi[4][4];
    float runR = 0.f, runI = 0.f;
#pragma unroll
    for (int mt = 0; mt < 4; ++mt)
#pragma unroll
      for (int r = 0; r < 4; ++r) {          // t increases by 1 each step
        float ur = acc[mt][2 * j][r], ui = acc[mt][2 * j + 1][r];
        runR += c_ * ur - s_ * ui;
        runI += c_ * ui + s_ * ur;
        vr[mt][r] = runR; vi[mt][r] = runI;
        float cn = c_ * c1v - s_ * s1v; s_ = s_ * c1v + c_ * s1v; c_ = cn;
      }
    // single cross-quad exclusive scan of 16-t segment totals
    float Qr = runR, Qi = runI;
    float arq = __shfl_xor(Qr, 16, 64), aiq = __shfl_xor(Qi, 16, 64);
    float brq = __shfl_xor(Qr, 32, 64), biq = __shfl_xor(Qi, 32, 64);
    float crq = __shfl_xor(brq, 16, 64), ciq = __shfl_xor(biq, 16, 64);
    float Sr = 0.f, Si = 0.f;
    if (quad & 1) { Sr += arq; Si += aiq; }
    if (quad & 2) { Sr += brq + crq; Si += biq + ciq; }
    float Er = carR + Sr, Ei = carI + Si;
#pragma unroll
    for (int mt = 0; mt < 4; ++mt)
#pragma unroll
      for (int r = 0; r < 4; ++r) {
        float pr = vr[mt][r] + Er, pi = vi[mt][r] + Ei;
        float rr2 = pr * pr + pi * pi;
        red[mt][r] += fmaxf(__builtin_amdgcn_sqrtf(norm2 * rr2 + 1e-8f) - biaso, 0.f);
      }
  }
#pragma unroll
  for (int mt = 0; mt < 4; ++mt)
#pragma unroll
    for (int r = 0; r < 4; ++r) {
      float v = row_sum16(red[mt][r]);        // valid at lrow==15
      if (lrow == 15) {
        int m = mbase + (quad << 4) + (mt << 2) + r;
        pooled[((size_t)m << 8) + o] = __float2bfloat16(v * (1.f / 32.f));
      }
    }
}

// ---------------------------------------------------------------------------
// gemm_k: BK=64 K-loop (half the barriers) + granule-XOR swizzle. B rows are
// PERMUTED in storage (see setup/prep2) -> lane owns 4 consecutive columns.
// EPI 1: +bias, SiLU, store packed bf16x4 ; EPI 2: +bias[z], store f32x4
// ---------------------------------------------------------------------------
template <int EPI>
__global__ __launch_bounds__(256, 2) void gemm_k(
    const bf16* __restrict__ A, const bf16* __restrict__ B, void* __restrict__ Cp,
    const float* __restrict__ bias, int N, int K,
    long long c_bstride, long long b_bstride, int bias_bstride) {
  __shared__ bf16 As[128 * 64];
  __shared__ bf16 Bs[128 * 64];
  const int tid = threadIdx.x;
  const int wave = tid >> 6, lane = tid & 63;
  const int wm = (wave >> 1) << 6, wn = (wave & 1) << 6;
  const int lrow = lane & 15, quad = lane >> 4;
  const int m0 = blockIdx.y << 7, n0 = blockIdx.x << 7;
  const int z = blockIdx.z;
  const bf16* Bz = B + (size_t)z * b_bstride;

  f32x4 acc[4][4] = {};
  for (int k0 = 0; k0 < K; k0 += 64) {
#pragma unroll
    for (int c = 0; c < 4; ++c) {
      int slot = (((wave << 2) + c) << 6) + lane;
      int row = slot >> 3;
      int g = (slot & 7) ^ (row & 7);
      int lq = slot << 4;
      gload16((const char*)A  + (((size_t)(m0 + row) * K + k0 + (g << 3)) << 1), (char*)As + lq);
      gload16((const char*)Bz + (((size_t)(n0 + row) * K + k0 + (g << 3)) << 1), (char*)Bs + lq);
    }
    __syncthreads();
#pragma unroll
    for (int kh = 0; kh < 2; ++kh) {
      bf16x8 af[4], bfr[4];
#pragma unroll
      for (int i = 0; i < 4; ++i) {
        int gg = ((((kh << 2) + quad) ^ (lrow & 7)) << 3);
        af[i]  = *(const bf16x8*)(As + ((wm + (i << 4) + lrow) << 6) + gg);
        bfr[i] = *(const bf16x8*)(Bs + ((wn + (i << 4) + lrow) << 6) + gg);
      }
#pragma unroll
      for (int mt = 0; mt < 4; ++mt)
#pragma unroll
        for (int nt = 0; nt < 4; ++nt)
          acc[mt][nt] = __builtin_amdgcn_mfma_f32_16x16x32_bf16(af[mt], bfr[nt], acc[mt][nt], 0, 0, 0);
    }
    __syncthreads();
  }

  const int gnb = n0 + wn + (lrow << 2);       // 4 consecutive true columns
  f32x4 b4;
  if (EPI == 1) b4 = *(const f32x4*)(bias + gnb);
  else          b4 = *(const f32x4*)(bias + (size_t)z * bias_bstride + gnb);

#pragma unroll
  for (int mt = 0; mt < 4; ++mt) {
#pragma unroll
    for (int r = 0; r < 4; ++r) {
      int gm = m0 + wm + (mt << 4) + (quad << 2) + r;
      if (EPI == 1) {
        union { bf16 h[4]; uint2 u; } pk;
#pragma unroll
        for (int nt = 0; nt < 4; ++nt) {
          float v = acc[mt][nt][r] + b4[nt];
          v = v / (1.f + __expf(-v));                    // SiLU
          pk.h[nt] = __float2bfloat16(v);
        }
        *(uint2*)((bf16*)Cp + (size_t)gm * N + gnb) = pk.u;
      } else {
        f32x4 vv;
#pragma unroll
        for (int nt = 0; nt < 4; ++nt) vv[nt] = acc[mt][nt][r] + b4[nt];
        *(f32x4*)((float*)Cp + (size_t)z * c_bstride + (size_t)gm * N + gnb) = vv;
      }
    }
  }
}

// ---------------------------------------------------------------------------
extern "C" void kernel_launch(void* const* d_in, const int* in_sizes, int n_in,
                              void* d_out, int out_size, void* d_ws, size_t ws_size,
                              hipStream_t stream) {
  const bf16* x        = (const bf16*)d_in[0];
  const bf16* conv_w   = (const bf16*)d_in[1];
  const bf16* mrb      = (const bf16*)d_in[2];
  const float* w_shared = (const float*)d_in[3];
  const float* b_shared = (const float*)d_in[4];
  const float* layer_w  = (const float*)d_in[5];
  const float* layer_b  = (const float*)d_in[6];
  float* out = (float*)d_out;

  char* ws = (char*)d_ws;
  bf16* Bmat    = (bf16*)(ws);                // 8,388,608
  bf16* W2      = (bf16*)(ws + 8388608);      // 8,388,608   -> 16,777,216
  bf16* Y2      = (bf16*)(ws + 16777216);     // 4,194,304   -> 20,971,520
  float* totals = (float*)(ws + 20971520);    // 4,194,304   -> 25,165,824
  bf16* pooled  = (bf16*)(ws + 25165824);     // 2,097,152   -> 27,262,976
  bf16* wsb     = (bf16*)(ws + 27262976);     // 393,216     -> 27,656,192
  bf16* hidden  = (bf16*)(ws + 27656192);     // 6,291,456   -> 33,947,648
  bf16* lwb     = (bf16*)(ws + 33947648);     // 9,437,184   -> 43,384,832

  // one fused setup dispatch: prep_t (256) | ybuild (256) | prep2 (512)
  setup<<<1024, 256, 0, stream>>>(conv_w, x, w_shared, layer_w, Bmat, W2, Y2, wsb, lwb);

  // chunk totals via the small algebraic path
  wtot<<<dim3(1, 2, K_MAX), 256, 0, stream>>>(W2, Y2, totals);
  tprefix<<<128, 256, 0, stream>>>(totals);

  // big GEMM pass: recompute u, prefix, modReLU, pool
  gemm_p<<<dim3(NU / 128, MTOT / 128, 1), 256, 0, stream>>>(x, Bmat, x, totals, mrb, pooled);

  // hidden = silu(pooled @ w_shared^T + b_shared)
  gemm_k<1><<<dim3(D_MODEL / 128, MTOT / 128, 1), 256, 0, stream>>>(
      pooled, wsb, hidden, b_shared, D_MODEL, D_SPEC, 0, 0, 0);

  // cond[l] = hidden @ layer_w[l]^T + layer_b[l]
  gemm_k<2><<<dim3(NCOND / 128, MTOT / 128, N_LAYERS), 256, 0, stream>>>(
      hidden, lwb, out, layer_b, NCOND, D_MODEL,
      (long long)MTOT * NCOND, (long long)NCOND * D_MODEL, NCOND);
}

// Round 14
// 267.436 us; speedup vs baseline: 1.3196x; 1.0031x over previous
//
#include <hip/hip_runtime.h>
#include <hip/hip_bf16.h>

typedef __hip_bfloat16 bf16;
typedef __attribute__((ext_vector_type(8))) short bf16x8;  // 8 bf16 in 4 VGPRs
typedef __attribute__((ext_vector_type(4))) float f32x4;

#define SEQ_LEN 2048
#define K_MAX   32
#define D_SPEC  256
#define D_MODEL 768
#define N_LAYERS 4
#define BATCH   2
#define MTOT    (BATCH * SEQ_LEN)       // 4096 rows (b*2048+t)
#define NU      (D_SPEC * K_MAX * 2)    // 16384 cols
#define NCOND   (2 * D_MODEL)           // 1536
#define NCHUNK  32

__device__ inline float b2f(bf16 h) { return __bfloat162float(h); }

__device__ inline void gload16(const void* gp, void* lp) {
  __builtin_amdgcn_global_load_lds((const __attribute__((address_space(1))) void*)gp,
                                   (__attribute__((address_space(3))) void*)lp, 16, 0, 0);
}

// (BK=32 helpers, still used by wtot)
__device__ inline int stage_c16(int lane) { return ((lane & 3) ^ ((lane >> 2) & 3) ^ ((lane >> 4) & 3)); }
__device__ inline int frag_off(int R, int q) {
  return (R << 5) + (((q ^ (R & 3) ^ ((R >> 2) & 3)) & 3) << 3);
}

// Full-rate DPP sum over each 16-lane row; result valid in lane 15 of each row.
__device__ inline float row_sum16(float v) {
  v += __int_as_float(__builtin_amdgcn_update_dpp(0, __float_as_int(v), 0x111, 0xF, 0xF, true)); // row_shr:1
  v += __int_as_float(__builtin_amdgcn_update_dpp(0, __float_as_int(v), 0x112, 0xF, 0xF, true)); // row_shr:2
  v += __int_as_float(__builtin_amdgcn_update_dpp(0, __float_as_int(v), 0x114, 0xF, 0xF, true)); // row_shr:4
  v += __int_as_float(__builtin_amdgcn_update_dpp(0, __float_as_int(v), 0x118, 0xF, 0xF, true)); // row_shr:8
  return v;
}

// ---------------------------------------------------------------------------
// setup: ONE dispatch doing all three prep jobs, split by blockIdx range.
//   Bmat now carries the x self-term folded in: Bmat[n][i] += (i==o, ri==0).
// ---------------------------------------------------------------------------
__global__ __launch_bounds__(256) void setup(
    const bf16* __restrict__ conv_w, const bf16* __restrict__ x,
    const float* __restrict__ w_shared, const float* __restrict__ layer_w,
    bf16* __restrict__ Bmat, bf16* __restrict__ W2, bf16* __restrict__ Y2,
    bf16* __restrict__ wsb, bf16* __restrict__ lwb) {
  __shared__ bf16 L[256][66];        // only used by prep_t blocks
  const int bid = blockIdx.x;
  const int tid = threadIdx.x;

  if (bid < 256) {                   // ---- prep_t ----
    const int o = bid;
    const bf16* src = conv_w + (size_t)o * 16384;
#pragma unroll
    for (int it = 0; it < 8; ++it) {
      int v = tid + (it << 8);
      int e = v << 3;
      int i = e >> 6, kc = e & 63;
      uint4 d = *(const uint4*)(src + e);
      *(unsigned*)&L[i][kc]     = d.x;
      *(unsigned*)&L[i][kc + 2] = d.y;
      *(unsigned*)&L[i][kc + 4] = d.z;
      *(unsigned*)&L[i][kc + 6] = d.w;
    }
    __syncthreads();
#pragma unroll
    for (int kc = 0; kc < 64; ++kc) {
      int n = ((o << 1) + (kc >> 5)) * 32 + ((kc & 1) << 4) + ((kc >> 1) & 15);
      bf16 v = L[tid][kc];
      if (tid == o && (kc & 1) == 0)           // fold x self-term: +1 on re-plane diag
        v = __float2bfloat16(1.0f + b2f(v));
      Bmat[((size_t)n << 8) + tid] = v;
    }
#pragma unroll
    for (int k = 0; k < 32; ++k) {
#pragma unroll
      for (int h = 0; h < 2; ++h) {
        int i2 = (h << 8) + tid;
        W2[((size_t)k << 17) + (o << 9) + i2] = L[i2 >> 1][(k << 1) + (i2 & 1)];
      }
    }
  } else if (bid < 512) {            // ---- ybuild ----
    const int yb = bid - 256;
    const int bc = yb >> 2, kg = (yb & 3) << 3;
    const int b = bc >> 5, c = bc & 31;
    const int t0 = c << 6;
    const int i = tid;
    const float c1f = -0.0030679615757712823f;
    float cs[8], sn[8], cd[8], sd[8], aC[8] = {}, aS[8] = {};
#pragma unroll
    for (int kk = 0; kk < 8; ++kk) {
      int k = kg + kk;
      __sincosf(c1f * (float)((t0 * k) & 2047), &sn[kk], &cs[kk]);
      __sincosf(c1f * (float)k, &sd[kk], &cd[kk]);
    }
    const bf16* xp = x + (((size_t)((b << 11) + t0)) << 8) + i;
#pragma unroll 4
    for (int t = 0; t < 64; ++t) {
      float xv = b2f(*xp); xp += D_SPEC;
#pragma unroll
      for (int kk = 0; kk < 8; ++kk) {
        aC[kk] += cs[kk] * xv; aS[kk] += sn[kk] * xv;
        float cn = cs[kk] * cd[kk] - sn[kk] * sd[kk];
        sn[kk] = sn[kk] * cd[kk] + cs[kk] * sd[kk];
        cs[kk] = cn;
      }
    }
#pragma unroll
    for (int kk = 0; kk < 8; ++kk) {
      int k = kg + kk;
      __hip_bfloat162 p0, p1;
      p0.x = __float2bfloat16(aC[kk]);  p0.y = __float2bfloat16(-aS[kk]);
      p1.x = __float2bfloat16(aS[kk]);  p1.y = __float2bfloat16(aC[kk]);
      *(__hip_bfloat162*)(Y2 + (((size_t)(k << 7) + (bc << 1)) << 9) + (i << 1)) = p0;
      *(__hip_bfloat162*)(Y2 + (((size_t)(k << 7) + (bc << 1) + 1) << 9) + (i << 1)) = p1;
    }
  } else {                           // ---- prep2 (row-permuted casts) ----
    int idx = (bid - 512) * 256 + tid;
    int stride = 512 * 256;
    for (int j = idx; j < D_MODEL * D_SPEC; j += stride) {
      int row = j >> 8, col = j & 255;
      int g = row >> 6, q = row & 63;
      int rt = (g << 6) + ((q & 15) << 2) + (q >> 4);
      wsb[j] = __float2bfloat16(w_shared[rt * D_SPEC + col]);
    }
    for (int j = idx; j < N_LAYERS * NCOND * D_MODEL; j += stride) {
      int zc = j / (NCOND * D_MODEL);
      int rem = j - zc * (NCOND * D_MODEL);
      int row = rem / D_MODEL, col = rem - row * D_MODEL;
      int g = row >> 6, q = row & 63;
      int rt = (g << 6) + ((q & 15) << 2) + (q >> 4);
      lwb[j] = __float2bfloat16(layer_w[(size_t)zc * NCOND * D_MODEL + rt * D_MODEL + col]);
    }
  }
}

// ---------------------------------------------------------------------------
// wtot: per-k complex GEMM totals[bc,o,k] = W[k] @ Y2[k]^T + self. (BK=32 core.)
// ---------------------------------------------------------------------------
__global__ __launch_bounds__(256, 2) void wtot(const bf16* __restrict__ W2,
                                               const bf16* __restrict__ Y2,
                                               float* __restrict__ totals) {
  __shared__ bf16 As[128 * 32];
  __shared__ bf16 Bs[128 * 32];
  const int tid = threadIdx.x;
  const int wave = tid >> 6, lane = tid & 63;
  const int wm = (wave >> 1) << 6, wn = (wave & 1) << 6;
  const int lrow = lane & 15, quad = lane >> 4;
  const int m0 = blockIdx.y << 7;
  const int z = blockIdx.z;
  const bf16* A = W2 + ((size_t)z << 17);
  const bf16* B = Y2 + ((size_t)z << 16);

  f32x4 acc[4][4] = {};
  for (int k0 = 0; k0 < 512; k0 += 32) {
#pragma unroll
    for (int c = 0; c < 2; ++c) {
      int rr = ((wave * 2 + c) << 4) + (lane >> 2);
      int cb = stage_c16(lane) << 4;
      int lq = (((wave * 2 + c) << 6) + lane) << 4;
      gload16((const char*)A + (((size_t)(m0 + rr) * 512 + k0) << 1) + cb, (char*)As + lq);
      gload16((const char*)B + (((size_t)rr * 512 + k0) << 1) + cb, (char*)Bs + lq);
    }
    __syncthreads();
    bf16x8 af[4], bfr[4];
#pragma unroll
    for (int i = 0; i < 4; ++i) {
      af[i]  = *(const bf16x8*)(As + frag_off(wm + (i << 4) + lrow, quad));
      bfr[i] = *(const bf16x8*)(Bs + frag_off(wn + (i << 4) + lrow, quad));
    }
#pragma unroll
    for (int mt = 0; mt < 4; ++mt)
#pragma unroll
      for (int nt = 0; nt < 4; ++nt)
        acc[mt][nt] = __builtin_amdgcn_mfma_f32_16x16x32_bf16(af[mt], bfr[nt], acc[mt][nt], 0, 0, 0);
    __syncthreads();
  }

#pragma unroll
  for (int mt = 0; mt < 4; ++mt)
#pragma unroll
    for (int nt = 0; nt < 4; ++nt)
#pragma unroll
      for (int r = 0; r < 4; ++r) {
        int o   = m0 + wm + (mt << 4) + (quad << 2) + r;
        int col = wn + (nt << 4) + lrow;
        int bc = col >> 1, comp = col & 1;
        float self = b2f(B[((size_t)col << 9) + (o << 1)]);
        totals[((((size_t)bc << 13) + (o << 5) + z) << 1) + comp] = acc[mt][nt][r] + self;
      }
}

// In-place exclusive prefix over chunks; one thread per (chain, component).
__global__ void tprefix(float* __restrict__ totals) {
  int id = blockIdx.x * blockDim.x + threadIdx.x;   // 32768 = (b, ok, comp)
  int comp = id & 1, ok = (id >> 1) & 8191, b = id >> 14;
  float s = 0.f;
  for (int cc = 0; cc < NCHUNK; ++cc) {
    size_t idx = (((((size_t)(b * NCHUNK + cc)) << 13) + ok) << 1) + comp;
    float t = totals[idx];
    totals[idx] = s;
    s += t;
  }
}

// ---------------------------------------------------------------------------
// gemm_p: BK=64 K-loop + A-ROW PERMUTATION (quad owns 16 contiguous t) +
// granule-XOR LDS swizzle. x self-term folded into Bmat (setup) — no epilogue
// x loads. Epilogue: tw recurrence + register prefix + one cross-quad scan
// per j -> modReLU -> DPP k-mean.
// ---------------------------------------------------------------------------
__global__ __launch_bounds__(256, 3) void gemm_p(
    const bf16* __restrict__ A, const bf16* __restrict__ B,
    const float* __restrict__ totals, const bf16* __restrict__ mrb, bf16* __restrict__ pooled) {
  __shared__ bf16 As[128 * 64];
  __shared__ bf16 Bs[128 * 64];
  const int tid = threadIdx.x;
  const int wave = tid >> 6, lane = tid & 63;
  const int wm = (wave >> 1) << 6, wn = (wave & 1) << 6;
  const int lrow = lane & 15, quad = lane >> 4;
  const int m0 = blockIdx.y << 7, n0 = blockIdx.x << 7;

  f32x4 acc[4][4] = {};
  for (int k0 = 0; k0 < D_SPEC; k0 += 64) {
#pragma unroll
    for (int c = 0; c < 4; ++c) {
      int slot = (((wave << 2) + c) << 6) + lane;
      int row = slot >> 3;
      int g = (slot & 7) ^ (row & 7);          // source granule (swizzle on source side)
      int s = row & 63;
      int rA = (row & 64) + (((s >> 2) & 3) << 4) + ((s >> 4) << 2) + (s & 3);  // permuted A row
      int lq = slot << 4;
      gload16((const char*)A + (((size_t)(m0 + rA)  * D_SPEC + k0 + (g << 3)) << 1), (char*)As + lq);
      gload16((const char*)B + (((size_t)(n0 + row) * D_SPEC + k0 + (g << 3)) << 1), (char*)Bs + lq);
    }
    __syncthreads();
#pragma unroll
    for (int kh = 0; kh < 2; ++kh) {
      bf16x8 af[4], bfr[4];
#pragma unroll
      for (int i = 0; i < 4; ++i) {
        int gg = ((((kh << 2) + quad) ^ (lrow & 7)) << 3);
        af[i]  = *(const bf16x8*)(As + ((wm + (i << 4) + lrow) << 6) + gg);
        bfr[i] = *(const bf16x8*)(Bs + ((wn + (i << 4) + lrow) << 6) + gg);
      }
#pragma unroll
      for (int mt = 0; mt < 4; ++mt)
#pragma unroll
        for (int nt = 0; nt < 4; ++nt)
          acc[mt][nt] = __builtin_amdgcn_mfma_f32_16x16x32_bf16(af[mt], bfr[nt], acc[mt][nt], 0, 0, 0);
    }
    __syncthreads();
  }

  const int mbase = m0 + wm;                 // 64-row slab == exactly one chunk
  const int b = mbase >> 11;
  const int chunk = (mbase >> 6) & 31;
  const int g0 = (n0 + wn) >> 5;             // even
  const int o = g0 >> 1;                     // lane-uniform

  const float c1f = -0.0030679615757712823f;  // -2*pi/2048
  const float norm2 = 0.00048828125f;         // 1/2048
  const float biaso = b2f(mrb[o]);

  float red[4][4] = {};
#pragma unroll
  for (int j = 0; j < 2; ++j) {
    const int kk = lrow + (j << 4);
    const int t00 = (mbase & 2047) + (quad << 4);
    float c_, s_, c1v, s1v;
    __sincosf(c1f * (float)((t00 * kk) & 2047), &s_, &c_);
    __sincosf(c1f * (float)kk, &s1v, &c1v);
    const int ok = ((g0 + j) << 4) + lrow;
    size_t tb = ((((size_t)(b * NCHUNK + chunk)) << 13) + ok) << 1;
    float carR = totals[tb], carI = totals[tb + 1];

    float vr[4][4], vi[4][4];
    float runR = 0.f, runI = 0.f;
#pragma unroll
    for (int mt = 0; mt < 4; ++mt)
#pragma unroll
      for (int r = 0; r < 4; ++r) {          // t increases by 1 each step
        float ur = acc[mt][2 * j][r], ui = acc[mt][2 * j + 1][r];
        runR += c_ * ur - s_ * ui;
        runI += c_ * ui + s_ * ur;
        vr[mt][r] = runR; vi[mt][r] = runI;
        float cn = c_ * c1v - s_ * s1v; s_ = s_ * c1v + c_ * s1v; c_ = cn;
      }
    // single cross-quad exclusive scan of 16-t segment totals
    float Qr = runR, Qi = runI;
    float arq = __shfl_xor(Qr, 16, 64), aiq = __shfl_xor(Qi, 16, 64);
    float brq = __shfl_xor(Qr, 32, 64), biq = __shfl_xor(Qi, 32, 64);
    float crq = __shfl_xor(brq, 16, 64), ciq = __shfl_xor(biq, 16, 64);
    float Sr = 0.f, Si = 0.f;
    if (quad & 1) { Sr += arq; Si += aiq; }
    if (quad & 2) { Sr += brq + crq; Si += biq + ciq; }
    float Er = carR + Sr, Ei = carI + Si;
#pragma unroll
    for (int mt = 0; mt < 4; ++mt)
#pragma unroll
      for (int r = 0; r < 4; ++r) {
        float pr = vr[mt][r] + Er, pi = vi[mt][r] + Ei;
        float rr2 = pr * pr + pi * pi;
        red[mt][r] += fmaxf(__builtin_amdgcn_sqrtf(norm2 * rr2 + 1e-8f) - biaso, 0.f);
      }
  }
#pragma unroll
  for (int mt = 0; mt < 4; ++mt)
#pragma unroll
    for (int r = 0; r < 4; ++r) {
      float v = row_sum16(red[mt][r]);        // valid at lrow==15
      if (lrow == 15) {
        int m = mbase + (quad << 4) + (mt << 2) + r;
        pooled[((size_t)m << 8) + o] = __float2bfloat16(v * (1.f / 32.f));
      }
    }
}

// ---------------------------------------------------------------------------
// gemm_k: BK=64 K-loop + granule-XOR swizzle. B rows PERMUTED in storage
// (see setup/prep2) -> lane owns 4 consecutive columns -> vector stores.
// EPI 1: +bias, SiLU, store packed bf16x4 ; EPI 2: +bias[z], store f32x4
// ---------------------------------------------------------------------------
template <int EPI>
__global__ __launch_bounds__(256, 2) void gemm_k(
    const bf16* __restrict__ A, const bf16* __restrict__ B, void* __restrict__ Cp,
    const float* __restrict__ bias, int N, int K,
    long long c_bstride, long long b_bstride, int bias_bstride) {
  __shared__ bf16 As[128 * 64];
  __shared__ bf16 Bs[128 * 64];
  const int tid = threadIdx.x;
  const int wave = tid >> 6, lane = tid & 63;
  const int wm = (wave >> 1) << 6, wn = (wave & 1) << 6;
  const int lrow = lane & 15, quad = lane >> 4;
  const int m0 = blockIdx.y << 7, n0 = blockIdx.x << 7;
  const int z = blockIdx.z;
  const bf16* Bz = B + (size_t)z * b_bstride;

  f32x4 acc[4][4] = {};
  for (int k0 = 0; k0 < K; k0 += 64) {
#pragma unroll
    for (int c = 0; c < 4; ++c) {
      int slot = (((wave << 2) + c) << 6) + lane;
      int row = slot >> 3;
      int g = (slot & 7) ^ (row & 7);
      int lq = slot << 4;
      gload16((const char*)A  + (((size_t)(m0 + row) * K + k0 + (g << 3)) << 1), (char*)As + lq);
      gload16((const char*)Bz + (((size_t)(n0 + row) * K + k0 + (g << 3)) << 1), (char*)Bs + lq);
    }
    __syncthreads();
#pragma unroll
    for (int kh = 0; kh < 2; ++kh) {
      bf16x8 af[4], bfr[4];
#pragma unroll
      for (int i = 0; i < 4; ++i) {
        int gg = ((((kh << 2) + quad) ^ (lrow & 7)) << 3);
        af[i]  = *(const bf16x8*)(As + ((wm + (i << 4) + lrow) << 6) + gg);
        bfr[i] = *(const bf16x8*)(Bs + ((wn + (i << 4) + lrow) << 6) + gg);
      }
#pragma unroll
      for (int mt = 0; mt < 4; ++mt)
#pragma unroll
        for (int nt = 0; nt < 4; ++nt)
          acc[mt][nt] = __builtin_amdgcn_mfma_f32_16x16x32_bf16(af[mt], bfr[nt], acc[mt][nt], 0, 0, 0);
    }
    __syncthreads();
  }

  const int gnb = n0 + wn + (lrow << 2);       // 4 consecutive true columns
  f32x4 b4;
  if (EPI == 1) b4 = *(const f32x4*)(bias + gnb);
  else          b4 = *(const f32x4*)(bias + (size_t)z * bias_bstride + gnb);

#pragma unroll
  for (int mt = 0; mt < 4; ++mt) {
#pragma unroll
    for (int r = 0; r < 4; ++r) {
      int gm = m0 + wm + (mt << 4) + (quad << 2) + r;
      if (EPI == 1) {
        union { bf16 h[4]; uint2 u; } pk;
#pragma unroll
        for (int nt = 0; nt < 4; ++nt) {
          float v = acc[mt][nt][r] + b4[nt];
          v = v / (1.f + __expf(-v));                    // SiLU
          pk.h[nt] = __float2bfloat16(v);
        }
        *(uint2*)((bf16*)Cp + (size_t)gm * N + gnb) = pk.u;
      } else {
        f32x4 vv;
#pragma unroll
        for (int nt = 0; nt < 4; ++nt) vv[nt] = acc[mt][nt][r] + b4[nt];
        *(f32x4*)((float*)Cp + (size_t)z * c_bstride + (size_t)gm * N + gnb) = vv;
      }
    }
  }
}

// ---------------------------------------------------------------------------
extern "C" void kernel_launch(void* const* d_in, const int* in_sizes, int n_in,
                              void* d_out, int out_size, void* d_ws, size_t ws_size,
                              hipStream_t stream) {
  const bf16* x        = (const bf16*)d_in[0];
  const bf16* conv_w   = (const bf16*)d_in[1];
  const bf16* mrb      = (const bf16*)d_in[2];
  const float* w_shared = (const float*)d_in[3];
  const float* b_shared = (const float*)d_in[4];
  const float* layer_w  = (const float*)d_in[5];
  const float* layer_b  = (const float*)d_in[6];
  float* out = (float*)d_out;

  char* ws = (char*)d_ws;
  bf16* Bmat    = (bf16*)(ws);                // 8,388,608
  bf16* W2      = (bf16*)(ws + 8388608);      // 8,388,608   -> 16,777,216
  bf16* Y2      = (bf16*)(ws + 16777216);     // 4,194,304   -> 20,971,520
  float* totals = (float*)(ws + 20971520);    // 4,194,304   -> 25,165,824
  bf16* pooled  = (bf16*)(ws + 25165824);     // 2,097,152   -> 27,262,976
  bf16* wsb     = (bf16*)(ws + 27262976);     // 393,216     -> 27,656,192
  bf16* hidden  = (bf16*)(ws + 27656192);     // 6,291,456   -> 33,947,648
  bf16* lwb     = (bf16*)(ws + 33947648);     // 9,437,184   -> 43,384,832

  // one fused setup dispatch: prep_t (256) | ybuild (256) | prep2 (512)
  setup<<<1024, 256, 0, stream>>>(conv_w, x, w_shared, layer_w, Bmat, W2, Y2, wsb, lwb);

  // chunk totals via the small algebraic path
  wtot<<<dim3(1, 2, K_MAX), 256, 0, stream>>>(W2, Y2, totals);
  tprefix<<<128, 256, 0, stream>>>(totals);

  // big GEMM pass (x folded into Bmat): prefix, modReLU, pool
  gemm_p<<<dim3(NU / 128, MTOT / 128, 1), 256, 0, stream>>>(x, Bmat, totals, mrb, pooled);

  // hidden = silu(pooled @ w_shared^T + b_shared)
  gemm_k<1><<<dim3(D_MODEL / 128, MTOT / 128, 1), 256, 0, stream>>>(
      pooled, wsb, hidden, b_shared, D_MODEL, D_SPEC, 0, 0, 0);

  // cond[l] = hidden @ layer_w[l]^T + layer_b[l]
  gemm_k<2><<<dim3(NCOND / 128, MTOT / 128, N_LAYERS), 256, 0, stream>>>(
      hidden, lwb, out, layer_b, NCOND, D_MODEL,
      (long long)MTOT * NCOND, (long long)NCOND * D_MODEL, NCOND);
}